// Round 1
// baseline (4232.117 us; speedup 1.0000x reference)
//
#include <hip/hip_runtime.h>
#include <math.h>

#define NEG 0.2f

__device__ __forceinline__ void atomAddF(float* p, float v) {
    unsafeAtomicAdd(p, v);   // hw global_atomic_add_f32 on gfx950
}

// ---------------------------------------------------------------------------
// K1: fused  xh = x@lin_w ; out = x@skip_w + skip_b + gat_bias ; a_src ; a_dst
// 256 threads/block, each thread owns one column of [lin_w | skip_w] in regs.
// Block processes 64 rows staged in LDS; broadcast ds_read feeds FMAs.
// ---------------------------------------------------------------------------
__global__ __launch_bounds__(256, 2) void k1_gemm(
    const float* __restrict__ x, const float* __restrict__ lin_w,
    const float* __restrict__ skip_w, const float* __restrict__ att_src,
    const float* __restrict__ att_dst, const float* __restrict__ gat_bias,
    const float* __restrict__ skip_b,
    float* __restrict__ xh, float* __restrict__ a_src, float* __restrict__ a_dst,
    float* __restrict__ out, int nrows)
{
    __shared__ float xs[64 * 128];
    const int t = threadIdx.x;
    const int row0 = blockIdx.x * 64;

    // W column in registers (compile-time indices only)
    float wcol[128];
    const float* wp = (t < 128) ? (lin_w + t) : (skip_w + (t - 128));
#pragma unroll
    for (int k = 0; k < 128; ++k) wcol[k] = wp[k * 128];

    float att_s = 0.f, att_d = 0.f, bias = 0.f;
    if (t < 128) { att_s = att_src[t]; att_d = att_dst[t]; }
    else         { bias = gat_bias[t - 128] + skip_b[t - 128]; }

    // stage x tile [64][128]
    {
        const float4* xg = (const float4*)(x + (size_t)row0 * 128);
        float4* xsv = (float4*)xs;
#pragma unroll
        for (int q = 0; q < 8; ++q) {
            int idx = q * 256 + t;          // 0..2047 float4 slots
            int r = idx >> 5;               // 32 float4 per row
            float4 v = make_float4(0.f, 0.f, 0.f, 0.f);
            if (row0 + r < nrows) v = xg[idx];
            xsv[idx] = v;
        }
    }
    __syncthreads();

    const int h = (t & 127) >> 4;           // head id for t<128
    for (int rg = 0; rg < 16; ++rg) {
        float a0 = 0.f, a1 = 0.f, a2 = 0.f, a3 = 0.f;
        const float4* xr0 = (const float4*)(xs + (rg * 4 + 0) * 128);
        const float4* xr1 = (const float4*)(xs + (rg * 4 + 1) * 128);
        const float4* xr2 = (const float4*)(xs + (rg * 4 + 2) * 128);
        const float4* xr3 = (const float4*)(xs + (rg * 4 + 3) * 128);
#pragma unroll
        for (int kq = 0; kq < 32; ++kq) {
            float4 v0 = xr0[kq], v1 = xr1[kq], v2 = xr2[kq], v3 = xr3[kq];
            float w0 = wcol[4 * kq], w1 = wcol[4 * kq + 1],
                  w2 = wcol[4 * kq + 2], w3 = wcol[4 * kq + 3];
            a0 += v0.x * w0 + v0.y * w1 + v0.z * w2 + v0.w * w3;
            a1 += v1.x * w0 + v1.y * w1 + v1.z * w2 + v1.w * w3;
            a2 += v2.x * w0 + v2.y * w1 + v2.z * w2 + v2.w * w3;
            a3 += v3.x * w0 + v3.y * w1 + v3.z * w2 + v3.w * w3;
        }
        float acc[4] = { a0, a1, a2, a3 };
#pragma unroll
        for (int r = 0; r < 4; ++r) {
            int grow = row0 + rg * 4 + r;
            if (t < 128) {
                float s = acc[r] * att_s;
                float d = acc[r] * att_d;
#pragma unroll
                for (int off = 8; off >= 1; off >>= 1) {
                    s += __shfl_xor(s, off, 16);
                    d += __shfl_xor(d, off, 16);
                }
                if (grow < nrows) {
                    xh[(size_t)grow * 128 + t] = acc[r];
                    if ((t & 15) == 0) {
                        a_src[(size_t)grow * 8 + h] = s;
                        a_dst[(size_t)grow * 8 + h] = d;
                    }
                }
            } else {
                if (grow < nrows)
                    out[(size_t)grow * 128 + (t - 128)] = acc[r] + bias;
            }
        }
    }
}

// ---------------------------------------------------------------------------
// K2: denom[i,h] += exp(leaky_relu(a_src[j,h] + a_dst[i,h]))
// one thread per (edge, head)
// ---------------------------------------------------------------------------
__global__ __launch_bounds__(256) void k2_denom(
    const int* __restrict__ ei, const float* __restrict__ a_src,
    const float* __restrict__ a_dst, float* __restrict__ denom,
    int E, int NE)
{
    int tid = blockIdx.x * 256 + threadIdx.x;
    int e = tid >> 3, h = tid & 7;
    if (e >= NE) return;
    int j, i;
    if (e < E) { j = ei[e]; i = ei[E + e]; }
    else       { j = i = e - E; }
    float v = a_src[(size_t)j * 8 + h] + a_dst[(size_t)i * 8 + h];
    v = v > 0.f ? v : NEG * v;
    atomAddF(denom + (size_t)i * 8 + h, __expf(v));
}

// ---------------------------------------------------------------------------
// K3: out[i,:] += alpha_ij * xh[j,:]   — one wave per edge, 2 ch/lane
// ---------------------------------------------------------------------------
__global__ __launch_bounds__(256) void k3_agg(
    const int* __restrict__ ei, const float* __restrict__ a_src,
    const float* __restrict__ a_dst, const float* __restrict__ denom,
    const float* __restrict__ xh, float* __restrict__ out, int E, int NE)
{
    int gid = blockIdx.x * 256 + threadIdx.x;
    int e = gid >> 6;
    if (e >= NE) return;
    int lane = threadIdx.x & 63;
    int j, i;
    if (e < E) { j = ei[e]; i = ei[E + e]; }
    else       { j = i = e - E; }
    int h = lane >> 3;
    float v = a_src[(size_t)j * 8 + h] + a_dst[(size_t)i * 8 + h];
    v = v > 0.f ? v : NEG * v;
    float alpha = __expf(v) / (denom[(size_t)i * 8 + h] + 1e-16f);
    float2 xv = *(const float2*)(xh + (size_t)j * 128 + lane * 2);
    atomAddF(out + (size_t)i * 128 + lane * 2,     alpha * xv.x);
    atomAddF(out + (size_t)i * 128 + lane * 2 + 1, alpha * xv.y);
}

// ---------------------------------------------------------------------------
// K4: in-place ELU
// ---------------------------------------------------------------------------
__global__ __launch_bounds__(256) void k4_elu(float* __restrict__ out, int n4)
{
    int idx = blockIdx.x * 256 + threadIdx.x;
    if (idx >= n4) return;
    float4 v = ((float4*)out)[idx];
    v.x = v.x > 0.f ? v.x : __expf(v.x) - 1.f;
    v.y = v.y > 0.f ? v.y : __expf(v.y) - 1.f;
    v.z = v.z > 0.f ? v.z : __expf(v.z) - 1.f;
    v.w = v.w > 0.f ? v.w : __expf(v.w) - 1.f;
    ((float4*)out)[idx] = v;
}

extern "C" void kernel_launch(void* const* d_in, const int* in_sizes, int n_in,
                              void* d_out, int out_size, void* d_ws, size_t ws_size,
                              hipStream_t stream)
{
    const float* x        = (const float*)d_in[0];
    const int*   ei       = (const int*)d_in[1];
    const float* lin_w    = (const float*)d_in[2];
    const float* att_src  = (const float*)d_in[3];
    const float* att_dst  = (const float*)d_in[4];
    const float* gat_bias = (const float*)d_in[5];
    const float* skip_w   = (const float*)d_in[6];
    const float* skip_b   = (const float*)d_in[7];
    float* out = (float*)d_out;

    const int N  = in_sizes[0] / 128;
    const int E  = in_sizes[1] / 2;
    const int NE = E + N;

    float* ws    = (float*)d_ws;
    float* xh    = ws;                         // N*128
    float* asrc  = xh   + (size_t)N * 128;     // N*8
    float* adst  = asrc + (size_t)N * 8;       // N*8
    float* denom = adst + (size_t)N * 8;       // N*8

    hipMemsetAsync(denom, 0, (size_t)N * 8 * sizeof(float), stream);

    k1_gemm<<<(N + 63) / 64, 256, 0, stream>>>(
        x, lin_w, skip_w, att_src, att_dst, gat_bias, skip_b,
        xh, asrc, adst, out, N);

    k2_denom<<<(NE * 8 + 255) / 256, 256, 0, stream>>>(ei, asrc, adst, denom, E, NE);

    k3_agg<<<(NE + 3) / 4, 256, 0, stream>>>(ei, asrc, adst, denom, xh, out, E, NE);

    k4_elu<<<(N * 32 + 255) / 256, 256, 0, stream>>>(out, N * 32);
}

// Round 2
// 510.092 us; speedup vs baseline: 8.2968x; 8.2968x over previous
//
#include <hip/hip_runtime.h>
#include <math.h>

#define NEG 0.2f

// ---------------------------------------------------------------------------
// K1: tiled GEMM: [N,128] @ [128, 256(lin|skip)] -> xh, out(=skip+biases),
// fused a_src/a_dst epilogue. Block tile 64x256, K-chunk 32, 8x8 micro-tile.
// ---------------------------------------------------------------------------
__global__ __launch_bounds__(256, 2) void k1_gemm(
    const float* __restrict__ x, const float* __restrict__ lin_w,
    const float* __restrict__ skip_w, const float* __restrict__ att_src,
    const float* __restrict__ att_dst, const float* __restrict__ gat_bias,
    const float* __restrict__ skip_b,
    float* __restrict__ xh, float* __restrict__ a_src, float* __restrict__ a_dst,
    float* __restrict__ out, int nrows)
{
    __shared__ float xs[64][32];     // 8 KB
    __shared__ float wsld[32][256];  // 32 KB
    const int t = threadIdx.x;
    const int row0 = blockIdx.x * 64;
    const int cg = t & 31;           // cols cg*8 .. cg*8+7
    const int rg = t >> 5;           // rows rg*8 .. rg*8+7

    float atts[8], attd[8], bb[8];
#pragma unroll
    for (int j = 0; j < 8; ++j) { atts[j] = 0.f; attd[j] = 0.f; bb[j] = 0.f; }
    if (cg < 16) {
#pragma unroll
        for (int j = 0; j < 8; ++j) {
            atts[j] = att_src[cg * 8 + j];
            attd[j] = att_dst[cg * 8 + j];
        }
    } else {
#pragma unroll
        for (int j = 0; j < 8; ++j) {
            int c = cg * 8 - 128 + j;
            bb[j] = gat_bias[c] + skip_b[c];
        }
    }

    float acc[8][8];
#pragma unroll
    for (int m = 0; m < 8; ++m)
#pragma unroll
        for (int j = 0; j < 8; ++j) acc[m][j] = 0.f;

    for (int kc = 0; kc < 4; ++kc) {
        {   // stage x chunk [64][32]
            int r = t >> 2, c0 = (t & 3) * 8;
            float4 v0 = make_float4(0.f, 0.f, 0.f, 0.f), v1 = v0;
            if (row0 + r < nrows) {
                const float* gp = x + (size_t)(row0 + r) * 128 + kc * 32 + c0;
                v0 = *(const float4*)gp;
                v1 = *(const float4*)(gp + 4);
            }
            *(float4*)&xs[r][c0] = v0;
            *(float4*)&xs[r][c0 + 4] = v1;
        }
        {   // stage w chunk [32][256]
            int wr = t >> 3, wc = (t & 7) * 32;
            const float* src = (wc < 128)
                ? (lin_w  + (size_t)(kc * 32 + wr) * 128 + wc)
                : (skip_w + (size_t)(kc * 32 + wr) * 128 + wc - 128);
#pragma unroll
            for (int q = 0; q < 8; ++q)
                *(float4*)&wsld[wr][wc + q * 4] = *(const float4*)(src + q * 4);
        }
        __syncthreads();
#pragma unroll
        for (int k4 = 0; k4 < 8; ++k4) {
            float4 xv[8];
#pragma unroll
            for (int m = 0; m < 8; ++m)
                xv[m] = *(const float4*)&xs[rg * 8 + m][k4 * 4];
#pragma unroll
            for (int kk = 0; kk < 4; ++kk) {
                float4 w0 = *(const float4*)&wsld[k4 * 4 + kk][cg * 8];
                float4 w1 = *(const float4*)&wsld[k4 * 4 + kk][cg * 8 + 4];
#pragma unroll
                for (int m = 0; m < 8; ++m) {
                    float a = kk == 0 ? xv[m].x : kk == 1 ? xv[m].y
                            : kk == 2 ? xv[m].z : xv[m].w;
                    acc[m][0] += a * w0.x; acc[m][1] += a * w0.y;
                    acc[m][2] += a * w0.z; acc[m][3] += a * w0.w;
                    acc[m][4] += a * w1.x; acc[m][5] += a * w1.y;
                    acc[m][6] += a * w1.z; acc[m][7] += a * w1.w;
                }
            }
        }
        __syncthreads();
    }

    // epilogue: stores + fused attention coefficients
#pragma unroll
    for (int m = 0; m < 8; ++m) {
        int row = row0 + rg * 8 + m;
        float s = 0.f, d = 0.f;
#pragma unroll
        for (int j = 0; j < 8; ++j) {
            s += acc[m][j] * atts[j];
            d += acc[m][j] * attd[j];
        }
        s += __shfl_xor(s, 1);
        d += __shfl_xor(d, 1);
        if (row < nrows) {
            if (cg < 16) {
                float4 v0 = make_float4(acc[m][0], acc[m][1], acc[m][2], acc[m][3]);
                float4 v1 = make_float4(acc[m][4], acc[m][5], acc[m][6], acc[m][7]);
                *(float4*)&xh[(size_t)row * 128 + cg * 8]     = v0;
                *(float4*)&xh[(size_t)row * 128 + cg * 8 + 4] = v1;
                if ((cg & 1) == 0) {
                    a_src[(size_t)row * 8 + (cg >> 1)] = s;
                    a_dst[(size_t)row * 8 + (cg >> 1)] = d;
                }
            } else {
                float4 v0 = make_float4(acc[m][0] + bb[0], acc[m][1] + bb[1],
                                        acc[m][2] + bb[2], acc[m][3] + bb[3]);
                float4 v1 = make_float4(acc[m][4] + bb[4], acc[m][5] + bb[5],
                                        acc[m][6] + bb[6], acc[m][7] + bb[7]);
                *(float4*)&out[(size_t)row * 128 + cg * 8 - 128]     = v0;
                *(float4*)&out[(size_t)row * 128 + cg * 8 - 128 + 4] = v1;
            }
        }
    }
}

// ---------------------------------------------------------------------------
// CSR build: histogram -> block scan -> block-sum scan -> rowptr -> scatter
// ---------------------------------------------------------------------------
__global__ __launch_bounds__(256) void k_hist(const int* __restrict__ ei,
                                              int* __restrict__ cnt, int E)
{
    int e = blockIdx.x * 256 + threadIdx.x;
    if (e < E) atomicAdd(&cnt[ei[E + e]], 1);
}

__global__ __launch_bounds__(256) void k_scan1(int* __restrict__ cnt,
                                               int* __restrict__ bsum, int n)
{
    __shared__ int s[256];
    int t = threadIdx.x, i = blockIdx.x * 256 + t;
    int v = (i < n) ? cnt[i] : 0;
    s[t] = v;
    __syncthreads();
    for (int off = 1; off < 256; off <<= 1) {
        int a = (t >= off) ? s[t - off] : 0;
        __syncthreads();
        s[t] += a;
        __syncthreads();
    }
    if (i < n) cnt[i] = s[t] - v;          // block-local exclusive, in place
    if (t == 255) bsum[blockIdx.x] = s[255];
}

__global__ __launch_bounds__(512) void k_scan2(const int* __restrict__ bsum,
                                               int* __restrict__ boff, int nb)
{
    __shared__ int s[512];
    int t = threadIdx.x;
    int v = (t < nb) ? bsum[t] : 0;
    s[t] = v;
    __syncthreads();
    for (int off = 1; off < 512; off <<= 1) {
        int a = (t >= off) ? s[t - off] : 0;
        __syncthreads();
        s[t] += a;
        __syncthreads();
    }
    if (t < nb) boff[t] = s[t] - v;        // exclusive
}

__global__ __launch_bounds__(256) void k_rp(int* __restrict__ pre,
                                            const int* __restrict__ boff,
                                            int* __restrict__ cur, int n)
{
    int i = blockIdx.x * 256 + threadIdx.x;
    if (i < n) {
        int rp = pre[i] + boff[i >> 8];
        pre[i] = rp;                        // now global exclusive = rowptr
        cur[i] = rp;
    }
}

__global__ __launch_bounds__(256) void k_scatter(const int* __restrict__ ei,
                                                 int* __restrict__ cur,
                                                 int* __restrict__ esrc, int E)
{
    int e = blockIdx.x * 256 + threadIdx.x;
    if (e < E) {
        int slot = atomicAdd(&cur[ei[E + e]], 1);
        esrc[slot] = ei[e];
    }
}

// ---------------------------------------------------------------------------
// K3: fused softmax-denominator + weighted aggregation + skip + ELU.
// One wave per node; lane owns channel pair (2*lane, 2*lane+1), h = lane>>3.
// out[i] = ELU( out[i] + (sum_j p_ij * xh[j]) / (sum_j p_ij + 1e-16) )
// (self loop handled analytically; division at end == per-edge alpha)
// ---------------------------------------------------------------------------
__global__ __launch_bounds__(256) void k3_agg(
    const int* __restrict__ rowptr, const int* __restrict__ rowend,
    const int* __restrict__ esrc,
    const float* __restrict__ a_src, const float* __restrict__ a_dst,
    const float* __restrict__ xh, float* __restrict__ out, int n)
{
    int i = blockIdx.x * 4 + (threadIdx.x >> 6);
    if (i >= n) return;
    int lane = threadIdx.x & 63;
    int h = lane >> 3;

    float adi = a_dst[(size_t)i * 8 + h];
    // self loop
    float e0 = a_src[(size_t)i * 8 + h] + adi;
    e0 = e0 > 0.f ? e0 : NEG * e0;
    float p = __expf(e0);
    float2 xv = *(const float2*)(xh + (size_t)i * 128 + lane * 2);
    float accx = p * xv.x, accy = p * xv.y, den = p;

    int k = rowptr[i], kend = rowend[i];
    int j = (k < kend) ? esrc[k] : 0;
    for (; k < kend; ++k) {
        int jn = (k + 1 < kend) ? esrc[k + 1] : 0;
        float ee = a_src[(size_t)j * 8 + h] + adi;
        ee = ee > 0.f ? ee : NEG * ee;
        float pp = __expf(ee);
        float2 xj = *(const float2*)(xh + (size_t)j * 128 + lane * 2);
        accx += pp * xj.x;
        accy += pp * xj.y;
        den += pp;
        j = jn;
    }

    float inv = 1.f / (den + 1e-16f);
    size_t o = (size_t)i * 128 + lane * 2;
    float o0 = out[o]     + accx * inv;
    float o1 = out[o + 1] + accy * inv;
    o0 = o0 > 0.f ? o0 : __expf(o0) - 1.f;
    o1 = o1 > 0.f ? o1 : __expf(o1) - 1.f;
    out[o]     = o0;
    out[o + 1] = o1;
}

extern "C" void kernel_launch(void* const* d_in, const int* in_sizes, int n_in,
                              void* d_out, int out_size, void* d_ws, size_t ws_size,
                              hipStream_t stream)
{
    const float* x        = (const float*)d_in[0];
    const int*   ei       = (const int*)d_in[1];
    const float* lin_w    = (const float*)d_in[2];
    const float* att_src  = (const float*)d_in[3];
    const float* att_dst  = (const float*)d_in[4];
    const float* gat_bias = (const float*)d_in[5];
    const float* skip_w   = (const float*)d_in[6];
    const float* skip_b   = (const float*)d_in[7];
    float* out = (float*)d_out;

    const int N = in_sizes[0] / 128;
    const int E = in_sizes[1] / 2;

    float* ws   = (float*)d_ws;
    float* xh   = ws;                          // N*128 f
    float* asrc = xh + (size_t)N * 128;        // N*8 f
    float* adst = asrc + (size_t)N * 8;        // N*8 f
    int* bufA = (int*)(adst + (size_t)N * 8);  // N int: cnt -> pre -> rowptr
    int* cur  = bufA + N;                      // N int: cursor -> rowend
    int* esrc = cur + N;                       // E int
    int* bsum = esrc + E;                      // <=512 int
    int* boff = bsum + 512;                    // <=512 int

    hipMemsetAsync(bufA, 0, (size_t)N * sizeof(int), stream);

    k1_gemm<<<(N + 63) / 64, 256, 0, stream>>>(
        x, lin_w, skip_w, att_src, att_dst, gat_bias, skip_b,
        xh, asrc, adst, out, N);

    k_hist<<<(E + 255) / 256, 256, 0, stream>>>(ei, bufA, E);

    int nb = (N + 255) / 256;                  // 391 <= 512
    k_scan1<<<nb, 256, 0, stream>>>(bufA, bsum, N);
    k_scan2<<<1, 512, 0, stream>>>(bsum, boff, nb);
    k_rp<<<nb, 256, 0, stream>>>(bufA, boff, cur, N);
    k_scatter<<<(E + 255) / 256, 256, 0, stream>>>(ei, cur, esrc, E);

    k3_agg<<<(N + 3) / 4, 256, 0, stream>>>(bufA, cur, esrc, asrc, adst, xh, out, N);
}

// Round 3
// 364.380 us; speedup vs baseline: 11.6146x; 1.3999x over previous
//
#include <hip/hip_runtime.h>
#include <math.h>

#define NEG 0.2f

typedef __attribute__((ext_vector_type(8))) short bf16x8;
typedef __attribute__((ext_vector_type(4))) float f32x4;

__device__ __forceinline__ unsigned short f2bf(float f) {
    unsigned u = __float_as_uint(f);
    u += 0x7fffu + ((u >> 16) & 1u);
    return (unsigned short)(u >> 16);
}
__device__ __forceinline__ float blo(unsigned v) { return __uint_as_float(v << 16); }
__device__ __forceinline__ float bhi(unsigned v) { return __uint_as_float(v & 0xffff0000u); }
__device__ __forceinline__ float lrexp(float v) {
    v = v > 0.f ? v : NEG * v;
    return __expf(v);
}

// ---------------------------------------------------------------------------
// K0: W^T precompute -> bf16  Wt[c][k] = W[k][c], c<128 lin, else skip
// ---------------------------------------------------------------------------
__global__ __launch_bounds__(256) void k0_wt(const float* __restrict__ lin_w,
                                             const float* __restrict__ skip_w,
                                             unsigned short* __restrict__ wt)
{
    int idx = blockIdx.x * 256 + threadIdx.x;   // 0..32767
    int k = idx >> 8, c = idx & 255;
    float v = (c < 128) ? lin_w[k * 128 + c] : skip_w[k * 128 + c - 128];
    wt[c * 128 + k] = f2bf(v);
}

// ---------------------------------------------------------------------------
// K1: bf16 MFMA GEMM  [64 rows, K=128] x [128, 256] per block.
// LDS: A 64x128 bf16 (16KB, XOR-swizzled) + B=Wt 256x128 bf16 (64KB, swizzled).
// 4 waves; wave w owns rows w*16..+15, all 256 cols (16 fragments).
// Epilogue: xh (bf16), a_src/a_dst (shfl reduce), out = skip + biases.
// ---------------------------------------------------------------------------
__global__ __launch_bounds__(256, 2) void k1_gemm(
    const float* __restrict__ x, const unsigned short* __restrict__ wt,
    const float* __restrict__ att_src, const float* __restrict__ att_dst,
    const float* __restrict__ gat_bias, const float* __restrict__ skip_b,
    unsigned short* __restrict__ xh_bf, float* __restrict__ a_src,
    float* __restrict__ a_dst, float* __restrict__ out, int nrows)
{
    extern __shared__ char lds[];   // [0,16384) = A, [16384, 81920) = B
    const int t = threadIdx.x;
    const int row0 = blockIdx.x * 64;

    // stage B: Wt [256][128] bf16, linear global -> swizzled LDS
#pragma unroll
    for (int q = 0; q < 16; ++q) {
        int c = q * 256 + t;                 // 16B chunk id, 0..4095
        int n = c >> 4, col8 = c & 15;
        uint4 v = *(const uint4*)(wt + n * 128 + col8 * 8);
        *(uint4*)(lds + 16384 + ((n * 256 + col8 * 16) ^ ((n & 7) << 4))) = v;
    }
    // stage A: x tile [64][128] fp32 -> bf16 swizzled LDS
#pragma unroll
    for (int q = 0; q < 4; ++q) {
        int c = q * 256 + t;                 // 0..1023
        int row = c >> 4, col8 = c & 15;
        float4 v0 = make_float4(0.f, 0.f, 0.f, 0.f), v1 = v0;
        if (row0 + row < nrows) {
            const float* gp = x + (size_t)(row0 + row) * 128 + col8 * 8;
            v0 = *(const float4*)gp;
            v1 = *(const float4*)(gp + 4);
        }
        bf16x8 b;
        b[0] = f2bf(v0.x); b[1] = f2bf(v0.y); b[2] = f2bf(v0.z); b[3] = f2bf(v0.w);
        b[4] = f2bf(v1.x); b[5] = f2bf(v1.y); b[6] = f2bf(v1.z); b[7] = f2bf(v1.w);
        *(bf16x8*)(lds + ((row * 256 + col8 * 16) ^ ((row & 7) << 4))) = b;
    }
    __syncthreads();

    const int w = t >> 6, l = t & 63, r = l & 15, half = l >> 4;
    f32x4 acc[16];
#pragma unroll
    for (int nt = 0; nt < 16; ++nt) acc[nt] = (f32x4){0.f, 0.f, 0.f, 0.f};

#pragma unroll
    for (int ks = 0; ks < 4; ++ks) {
        const int co = ks * 64 + half * 16;      // byte offset in row (8 bf16)
        const int arow = w * 16 + r;
        bf16x8 a = *(const bf16x8*)(lds + ((arow * 256 + co) ^ ((r & 7) << 4)));
#pragma unroll
        for (int nt = 0; nt < 16; ++nt) {
            int n = nt * 16 + r;
            bf16x8 b = *(const bf16x8*)(lds + 16384 + ((n * 256 + co) ^ ((r & 7) << 4)));
            acc[nt] = __builtin_amdgcn_mfma_f32_16x16x32_bf16(a, b, acc[nt], 0, 0, 0);
        }
    }

    // epilogue — lin half: xh + attention coefficients
#pragma unroll
    for (int nt = 0; nt < 8; ++nt) {
        float as_ = att_src[nt * 16 + r];
        float ad_ = att_dst[nt * 16 + r];
#pragma unroll
        for (int q = 0; q < 4; ++q) {
            int row = row0 + w * 16 + half * 4 + q;
            float v = acc[nt][q];
            float s = v * as_, d = v * ad_;
            s += __shfl_xor(s, 1, 16); d += __shfl_xor(d, 1, 16);
            s += __shfl_xor(s, 2, 16); d += __shfl_xor(d, 2, 16);
            s += __shfl_xor(s, 4, 16); d += __shfl_xor(d, 4, 16);
            s += __shfl_xor(s, 8, 16); d += __shfl_xor(d, 8, 16);
            if (row < nrows) {
                xh_bf[(size_t)row * 128 + nt * 16 + r] = f2bf(v);
                if (r == 0) {
                    a_src[(size_t)row * 8 + nt] = s;
                    a_dst[(size_t)row * 8 + nt] = d;
                }
            }
        }
    }
    // skip half: out = acc + gat_bias + skip_b
#pragma unroll
    for (int nt = 8; nt < 16; ++nt) {
        int c = (nt - 8) * 16 + r;
        float bb = gat_bias[c] + skip_b[c];
#pragma unroll
        for (int q = 0; q < 4; ++q) {
            int row = row0 + w * 16 + half * 4 + q;
            if (row < nrows) out[(size_t)row * 128 + c] = acc[nt][q] + bb;
        }
    }
}

// ---------------------------------------------------------------------------
// CSR build: histogram -> block scan -> block-sum scan -> rowptr -> scatter
// ---------------------------------------------------------------------------
__global__ __launch_bounds__(256) void k_hist(const int* __restrict__ ei,
                                              int* __restrict__ cnt, int E)
{
    int e = blockIdx.x * 256 + threadIdx.x;
    if (e < E) atomicAdd(&cnt[ei[E + e]], 1);
}

__global__ __launch_bounds__(256) void k_scan1(int* __restrict__ cnt,
                                               int* __restrict__ bsum, int n)
{
    __shared__ int s[256];
    int t = threadIdx.x, i = blockIdx.x * 256 + t;
    int v = (i < n) ? cnt[i] : 0;
    s[t] = v;
    __syncthreads();
    for (int off = 1; off < 256; off <<= 1) {
        int a = (t >= off) ? s[t - off] : 0;
        __syncthreads();
        s[t] += a;
        __syncthreads();
    }
    if (i < n) cnt[i] = s[t] - v;
    if (t == 255) bsum[blockIdx.x] = s[255];
}

__global__ __launch_bounds__(512) void k_scan2(const int* __restrict__ bsum,
                                               int* __restrict__ boff, int nb)
{
    __shared__ int s[512];
    int t = threadIdx.x;
    int v = (t < nb) ? bsum[t] : 0;
    s[t] = v;
    __syncthreads();
    for (int off = 1; off < 512; off <<= 1) {
        int a = (t >= off) ? s[t - off] : 0;
        __syncthreads();
        s[t] += a;
        __syncthreads();
    }
    if (t < nb) boff[t] = s[t] - v;
}

__global__ __launch_bounds__(256) void k_rp(int* __restrict__ pre,
                                            const int* __restrict__ boff,
                                            int* __restrict__ cur, int n)
{
    int i = blockIdx.x * 256 + threadIdx.x;
    if (i < n) {
        int rp = pre[i] + boff[i >> 8];
        pre[i] = rp;
        cur[i] = rp;
    }
}

__global__ __launch_bounds__(256) void k_scatter(const int* __restrict__ ei,
                                                 int* __restrict__ cur,
                                                 int* __restrict__ esrc, int E)
{
    int e = blockIdx.x * 256 + threadIdx.x;
    if (e < E) {
        int slot = atomicAdd(&cur[ei[E + e]], 1);
        esrc[slot] = ei[e];
    }
}

// ---------------------------------------------------------------------------
// K3: fused denom + aggregation + skip + ELU. One wave per node, bf16 xh,
// edge loop unrolled x4 for MLP.
// ---------------------------------------------------------------------------
__global__ __launch_bounds__(256) void k3_agg(
    const int* __restrict__ rowptr, const int* __restrict__ rowend,
    const int* __restrict__ esrc,
    const float* __restrict__ a_src, const float* __restrict__ a_dst,
    const unsigned int* __restrict__ xh32, float* __restrict__ out, int n)
{
    int i = blockIdx.x * 4 + (threadIdx.x >> 6);
    if (i >= n) return;
    int lane = threadIdx.x & 63;
    int h = lane >> 3;

    float adi = a_dst[(size_t)i * 8 + h];
    // self loop
    float p0 = lrexp(a_src[(size_t)i * 8 + h] + adi);
    unsigned u = xh32[(size_t)i * 64 + lane];
    float accx = p0 * blo(u), accy = p0 * bhi(u), den = p0;

    int k = rowptr[i], kend = rowend[i];
    for (; k + 4 <= kend; k += 4) {
        int j0 = esrc[k], j1 = esrc[k + 1], j2 = esrc[k + 2], j3 = esrc[k + 3];
        float s0 = a_src[(size_t)j0 * 8 + h];
        float s1 = a_src[(size_t)j1 * 8 + h];
        float s2 = a_src[(size_t)j2 * 8 + h];
        float s3 = a_src[(size_t)j3 * 8 + h];
        unsigned u0 = xh32[(size_t)j0 * 64 + lane];
        unsigned u1 = xh32[(size_t)j1 * 64 + lane];
        unsigned u2 = xh32[(size_t)j2 * 64 + lane];
        unsigned u3 = xh32[(size_t)j3 * 64 + lane];
        float p;
        p = lrexp(s0 + adi); accx += p * blo(u0); accy += p * bhi(u0); den += p;
        p = lrexp(s1 + adi); accx += p * blo(u1); accy += p * bhi(u1); den += p;
        p = lrexp(s2 + adi); accx += p * blo(u2); accy += p * bhi(u2); den += p;
        p = lrexp(s3 + adi); accx += p * blo(u3); accy += p * bhi(u3); den += p;
    }
    for (; k < kend; ++k) {
        int j = esrc[k];
        float p = lrexp(a_src[(size_t)j * 8 + h] + adi);
        unsigned uj = xh32[(size_t)j * 64 + lane];
        accx += p * blo(uj); accy += p * bhi(uj); den += p;
    }

    float inv = 1.f / (den + 1e-16f);
    size_t o = (size_t)i * 128 + lane * 2;
    float o0 = out[o]     + accx * inv;
    float o1 = out[o + 1] + accy * inv;
    o0 = o0 > 0.f ? o0 : __expf(o0) - 1.f;
    o1 = o1 > 0.f ? o1 : __expf(o1) - 1.f;
    out[o]     = o0;
    out[o + 1] = o1;
}

extern "C" void kernel_launch(void* const* d_in, const int* in_sizes, int n_in,
                              void* d_out, int out_size, void* d_ws, size_t ws_size,
                              hipStream_t stream)
{
    const float* x        = (const float*)d_in[0];
    const int*   ei       = (const int*)d_in[1];
    const float* lin_w    = (const float*)d_in[2];
    const float* att_src  = (const float*)d_in[3];
    const float* att_dst  = (const float*)d_in[4];
    const float* gat_bias = (const float*)d_in[5];
    const float* skip_w   = (const float*)d_in[6];
    const float* skip_b   = (const float*)d_in[7];
    float* out = (float*)d_out;

    const int N = in_sizes[0] / 128;
    const int E = in_sizes[1] / 2;

    float* ws   = (float*)d_ws;
    float* asrc = ws;                                   // N*8 f
    float* adst = asrc + (size_t)N * 8;                 // N*8 f
    unsigned short* wt    = (unsigned short*)(adst + (size_t)N * 8);  // 32768 bf16
    unsigned short* xh_bf = wt + 32768;                 // N*128 bf16
    int* bufA = (int*)(xh_bf + (size_t)N * 128);        // N int
    int* cur  = bufA + N;                               // N int
    int* esrc = cur + N;                                // E int
    int* bsum = esrc + E;                               // <=512
    int* boff = bsum + 512;                             // <=512

    hipMemsetAsync(bufA, 0, (size_t)N * sizeof(int), stream);

    k0_wt<<<128, 256, 0, stream>>>(lin_w, skip_w, wt);

    (void)hipFuncSetAttribute((const void*)k1_gemm,
                              hipFuncAttributeMaxDynamicSharedMemorySize, 81920);
    k1_gemm<<<(N + 63) / 64, 256, 81920, stream>>>(
        x, wt, att_src, att_dst, gat_bias, skip_b, xh_bf, asrc, adst, out, N);

    k_hist<<<(E + 255) / 256, 256, 0, stream>>>(ei, bufA, E);

    int nb = (N + 255) / 256;
    k_scan1<<<nb, 256, 0, stream>>>(bufA, bsum, N);
    k_scan2<<<1, 512, 0, stream>>>(bsum, boff, nb);
    k_rp<<<nb, 256, 0, stream>>>(bufA, boff, cur, N);
    k_scatter<<<(E + 255) / 256, 256, 0, stream>>>(ei, cur, esrc, E);

    k3_agg<<<(N + 3) / 4, 256, 0, stream>>>(bufA, cur, esrc, asrc, adst,
                                            (const unsigned int*)xh_bf, out, N);
}

// Round 4
// 321.340 us; speedup vs baseline: 13.1702x; 1.1339x over previous
//
#include <hip/hip_runtime.h>
#include <math.h>

#define NEG 0.2f

typedef __attribute__((ext_vector_type(8))) short bf16x8;
typedef __attribute__((ext_vector_type(4))) float f32x4;

__device__ __forceinline__ unsigned short f2bf(float f) {
    unsigned u = __float_as_uint(f);
    u += 0x7fffu + ((u >> 16) & 1u);
    return (unsigned short)(u >> 16);
}
__device__ __forceinline__ float blo(unsigned v) { return __uint_as_float(v << 16); }
__device__ __forceinline__ float bhi(unsigned v) { return __uint_as_float(v & 0xffff0000u); }
__device__ __forceinline__ float lrexp(float v) {
    v = v > 0.f ? v : NEG * v;
    return __expf(v);
}

// ---------------------------------------------------------------------------
// K0: W^T precompute -> bf16  Wt[c][k] = W[k][c], c<128 lin, else skip
// ---------------------------------------------------------------------------
__global__ __launch_bounds__(256) void k0_wt(const float* __restrict__ lin_w,
                                             const float* __restrict__ skip_w,
                                             unsigned short* __restrict__ wt)
{
    int idx = blockIdx.x * 256 + threadIdx.x;   // 0..32767
    int k = idx >> 8, c = idx & 255;
    float v = (c < 128) ? lin_w[k * 128 + c] : skip_w[k * 128 + c - 128];
    wt[c * 128 + k] = f2bf(v);
}

// ---------------------------------------------------------------------------
// K1: bf16 MFMA GEMM  [64 rows, K=128] x [128, 256] per block.
// ---------------------------------------------------------------------------
__global__ __launch_bounds__(256, 2) void k1_gemm(
    const float* __restrict__ x, const unsigned short* __restrict__ wt,
    const float* __restrict__ att_src, const float* __restrict__ att_dst,
    const float* __restrict__ gat_bias, const float* __restrict__ skip_b,
    unsigned short* __restrict__ xh_bf, float* __restrict__ a_src,
    float* __restrict__ a_dst, float* __restrict__ out, int nrows)
{
    extern __shared__ char lds[];   // [0,16384) = A, [16384, 81920) = B
    const int t = threadIdx.x;
    const int row0 = blockIdx.x * 64;

#pragma unroll
    for (int q = 0; q < 16; ++q) {
        int c = q * 256 + t;                 // 16B chunk id, 0..4095
        int n = c >> 4, col8 = c & 15;
        uint4 v = *(const uint4*)(wt + n * 128 + col8 * 8);
        *(uint4*)(lds + 16384 + ((n * 256 + col8 * 16) ^ ((n & 7) << 4))) = v;
    }
#pragma unroll
    for (int q = 0; q < 4; ++q) {
        int c = q * 256 + t;                 // 0..1023
        int row = c >> 4, col8 = c & 15;
        float4 v0 = make_float4(0.f, 0.f, 0.f, 0.f), v1 = v0;
        if (row0 + row < nrows) {
            const float* gp = x + (size_t)(row0 + row) * 128 + col8 * 8;
            v0 = *(const float4*)gp;
            v1 = *(const float4*)(gp + 4);
        }
        bf16x8 b;
        b[0] = f2bf(v0.x); b[1] = f2bf(v0.y); b[2] = f2bf(v0.z); b[3] = f2bf(v0.w);
        b[4] = f2bf(v1.x); b[5] = f2bf(v1.y); b[6] = f2bf(v1.z); b[7] = f2bf(v1.w);
        *(bf16x8*)(lds + ((row * 256 + col8 * 16) ^ ((row & 7) << 4))) = b;
    }
    __syncthreads();

    const int w = t >> 6, l = t & 63, r = l & 15, half = l >> 4;
    f32x4 acc[16];
#pragma unroll
    for (int nt = 0; nt < 16; ++nt) acc[nt] = (f32x4){0.f, 0.f, 0.f, 0.f};

#pragma unroll
    for (int ks = 0; ks < 4; ++ks) {
        const int co = ks * 64 + half * 16;
        const int arow = w * 16 + r;
        bf16x8 a = *(const bf16x8*)(lds + ((arow * 256 + co) ^ ((r & 7) << 4)));
#pragma unroll
        for (int nt = 0; nt < 16; ++nt) {
            int n = nt * 16 + r;
            bf16x8 b = *(const bf16x8*)(lds + 16384 + ((n * 256 + co) ^ ((r & 7) << 4)));
            acc[nt] = __builtin_amdgcn_mfma_f32_16x16x32_bf16(a, b, acc[nt], 0, 0, 0);
        }
    }

#pragma unroll
    for (int nt = 0; nt < 8; ++nt) {
        float as_ = att_src[nt * 16 + r];
        float ad_ = att_dst[nt * 16 + r];
#pragma unroll
        for (int q = 0; q < 4; ++q) {
            int row = row0 + w * 16 + half * 4 + q;
            float v = acc[nt][q];
            float s = v * as_, d = v * ad_;
            s += __shfl_xor(s, 1, 16); d += __shfl_xor(d, 1, 16);
            s += __shfl_xor(s, 2, 16); d += __shfl_xor(d, 2, 16);
            s += __shfl_xor(s, 4, 16); d += __shfl_xor(d, 4, 16);
            s += __shfl_xor(s, 8, 16); d += __shfl_xor(d, 8, 16);
            if (row < nrows) {
                xh_bf[(size_t)row * 128 + nt * 16 + r] = f2bf(v);
                if (r == 0) {
                    a_src[(size_t)row * 8 + nt] = s;
                    a_dst[(size_t)row * 8 + nt] = d;
                }
            }
        }
    }
#pragma unroll
    for (int nt = 8; nt < 16; ++nt) {
        int c = (nt - 8) * 16 + r;
        float bb = gat_bias[c] + skip_b[c];
#pragma unroll
        for (int q = 0; q < 4; ++q) {
            int row = row0 + w * 16 + half * 4 + q;
            if (row < nrows) out[(size_t)row * 128 + c] = acc[nt][q] + bb;
        }
    }
}

// ---------------------------------------------------------------------------
// CSR build, R4: coarse-binned scatter for write locality.
// bucket = dst >> 11 (2048 nodes/bucket, <=49 buckets, pad to 64)
// ---------------------------------------------------------------------------
__global__ __launch_bounds__(256) void kA_hist(const int* __restrict__ ei,
                                               int* __restrict__ node_cnt,
                                               int* __restrict__ bucket_cnt, int E)
{
    __shared__ int h[64];
    int t = threadIdx.x;
    if (t < 64) h[t] = 0;
    __syncthreads();
    int eb = blockIdx.x * 4096;
#pragma unroll
    for (int u = 0; u < 16; ++u) {
        int e = eb + u * 256 + t;
        if (e < E) {
            int d = ei[E + e];
            atomicAdd(&node_cnt[d], 1);
            atomicAdd(&h[d >> 11], 1);
        }
    }
    __syncthreads();
    if (t < 64 && h[t]) atomicAdd(&bucket_cnt[t], h[t]);
}

__global__ void k_bscan(const int* __restrict__ bucket_cnt,
                        int* __restrict__ bucket_cur)
{
    int t = threadIdx.x;                 // 64 threads
    int c = bucket_cnt[t];
    int v = c;
    for (int off = 1; off < 64; off <<= 1) {
        int a = __shfl_up(v, off);
        if (t >= off) v += a;
    }
    bucket_cur[t] = v - c;               // exclusive scan
}

__global__ __launch_bounds__(256) void kB_bin(const int* __restrict__ ei,
                                              int* __restrict__ bucket_cur,
                                              unsigned long long* __restrict__ binned,
                                              int E)
{
    __shared__ int h[64];
    __shared__ int base_[64];
    int t = threadIdx.x;
    if (t < 64) h[t] = 0;
    __syncthreads();
    int eb = blockIdx.x * 4096;
    int srcv[16], dstv[16], rkv[16];
#pragma unroll
    for (int u = 0; u < 16; ++u) {
        int e = eb + u * 256 + t;
        srcv[u] = 0; dstv[u] = -1; rkv[u] = 0;
        if (e < E) {
            srcv[u] = ei[e];
            dstv[u] = ei[E + e];
            rkv[u] = atomicAdd(&h[dstv[u] >> 11], 1);
        }
    }
    __syncthreads();
    if (t < 64) {
        int c = h[t];
        base_[t] = c ? atomicAdd(&bucket_cur[t], c) : 0;
    }
    __syncthreads();
#pragma unroll
    for (int u = 0; u < 16; ++u) {
        if (dstv[u] >= 0) {
            int b = dstv[u] >> 11;
            binned[base_[b] + rkv[u]] =
                ((unsigned long long)(unsigned)dstv[u] << 32) | (unsigned)srcv[u];
        }
    }
}

__global__ __launch_bounds__(256) void kC_scatter(
    const unsigned long long* __restrict__ binned,
    int* __restrict__ cur, int* __restrict__ esrc, int E)
{
    int e = blockIdx.x * 256 + threadIdx.x;
    if (e < E) {
        unsigned long long p = binned[e];
        int d = (int)(p >> 32), s = (int)(p & 0xffffffffu);
        int slot = atomicAdd(&cur[d], 1);
        esrc[slot] = s;
    }
}

// node-level scans (unchanged)
__global__ __launch_bounds__(256) void k_scan1(int* __restrict__ cnt,
                                               int* __restrict__ bsum, int n)
{
    __shared__ int s[256];
    int t = threadIdx.x, i = blockIdx.x * 256 + t;
    int v = (i < n) ? cnt[i] : 0;
    s[t] = v;
    __syncthreads();
    for (int off = 1; off < 256; off <<= 1) {
        int a = (t >= off) ? s[t - off] : 0;
        __syncthreads();
        s[t] += a;
        __syncthreads();
    }
    if (i < n) cnt[i] = s[t] - v;
    if (t == 255) bsum[blockIdx.x] = s[255];
}

__global__ __launch_bounds__(512) void k_scan2(const int* __restrict__ bsum,
                                               int* __restrict__ boff, int nb)
{
    __shared__ int s[512];
    int t = threadIdx.x;
    int v = (t < nb) ? bsum[t] : 0;
    s[t] = v;
    __syncthreads();
    for (int off = 1; off < 512; off <<= 1) {
        int a = (t >= off) ? s[t - off] : 0;
        __syncthreads();
        s[t] += a;
        __syncthreads();
    }
    if (t < nb) boff[t] = s[t] - v;
}

__global__ __launch_bounds__(256) void k_rp(int* __restrict__ pre,
                                            const int* __restrict__ boff,
                                            int* __restrict__ cur, int n)
{
    int i = blockIdx.x * 256 + threadIdx.x;
    if (i < n) {
        int rp = pre[i] + boff[i >> 8];
        pre[i] = rp;
        cur[i] = rp;
    }
}

// ---------------------------------------------------------------------------
// K3: fused denom + aggregation + skip + ELU (unchanged from R3)
// ---------------------------------------------------------------------------
__global__ __launch_bounds__(256) void k3_agg(
    const int* __restrict__ rowptr, const int* __restrict__ rowend,
    const int* __restrict__ esrc,
    const float* __restrict__ a_src, const float* __restrict__ a_dst,
    const unsigned int* __restrict__ xh32, float* __restrict__ out, int n)
{
    int i = blockIdx.x * 4 + (threadIdx.x >> 6);
    if (i >= n) return;
    int lane = threadIdx.x & 63;
    int h = lane >> 3;

    float adi = a_dst[(size_t)i * 8 + h];
    float p0 = lrexp(a_src[(size_t)i * 8 + h] + adi);
    unsigned u = xh32[(size_t)i * 64 + lane];
    float accx = p0 * blo(u), accy = p0 * bhi(u), den = p0;

    int k = rowptr[i], kend = rowend[i];
    for (; k + 4 <= kend; k += 4) {
        int j0 = esrc[k], j1 = esrc[k + 1], j2 = esrc[k + 2], j3 = esrc[k + 3];
        float s0 = a_src[(size_t)j0 * 8 + h];
        float s1 = a_src[(size_t)j1 * 8 + h];
        float s2 = a_src[(size_t)j2 * 8 + h];
        float s3 = a_src[(size_t)j3 * 8 + h];
        unsigned u0 = xh32[(size_t)j0 * 64 + lane];
        unsigned u1 = xh32[(size_t)j1 * 64 + lane];
        unsigned u2 = xh32[(size_t)j2 * 64 + lane];
        unsigned u3 = xh32[(size_t)j3 * 64 + lane];
        float p;
        p = lrexp(s0 + adi); accx += p * blo(u0); accy += p * bhi(u0); den += p;
        p = lrexp(s1 + adi); accx += p * blo(u1); accy += p * bhi(u1); den += p;
        p = lrexp(s2 + adi); accx += p * blo(u2); accy += p * bhi(u2); den += p;
        p = lrexp(s3 + adi); accx += p * blo(u3); accy += p * bhi(u3); den += p;
    }
    for (; k < kend; ++k) {
        int j = esrc[k];
        float p = lrexp(a_src[(size_t)j * 8 + h] + adi);
        unsigned uj = xh32[(size_t)j * 64 + lane];
        accx += p * blo(uj); accy += p * bhi(uj); den += p;
    }

    float inv = 1.f / (den + 1e-16f);
    size_t o = (size_t)i * 128 + lane * 2;
    float o0 = out[o]     + accx * inv;
    float o1 = out[o + 1] + accy * inv;
    o0 = o0 > 0.f ? o0 : __expf(o0) - 1.f;
    o1 = o1 > 0.f ? o1 : __expf(o1) - 1.f;
    out[o]     = o0;
    out[o + 1] = o1;
}

extern "C" void kernel_launch(void* const* d_in, const int* in_sizes, int n_in,
                              void* d_out, int out_size, void* d_ws, size_t ws_size,
                              hipStream_t stream)
{
    const float* x        = (const float*)d_in[0];
    const int*   ei       = (const int*)d_in[1];
    const float* lin_w    = (const float*)d_in[2];
    const float* att_src  = (const float*)d_in[3];
    const float* att_dst  = (const float*)d_in[4];
    const float* gat_bias = (const float*)d_in[5];
    const float* skip_b   = (const float*)d_in[7];
    const float* skip_w   = (const float*)d_in[6];
    float* out = (float*)d_out;

    const int N = in_sizes[0] / 128;
    const int E = in_sizes[1] / 2;

    float* ws   = (float*)d_ws;
    float* asrc = ws;                                   // N*8 f
    float* adst = asrc + (size_t)N * 8;                 // N*8 f
    unsigned short* wt    = (unsigned short*)(adst + (size_t)N * 8);  // 32768 bf16
    unsigned short* xh_bf = wt + 32768;                 // N*128 bf16
    int* bufA = (int*)(xh_bf + (size_t)N * 128);        // N int: cnt->rowptr
    int* cur  = bufA + N;                               // N int: cursor->rowend
    int* esrc = cur + N;                                // E int
    int* bsum = esrc + E;                               // 512
    int* boff = bsum + 512;                             // 512
    int* bucket_cnt = boff + 512;                       // 64
    int* bucket_cur = bucket_cnt + 64;                  // 64
    unsigned long long* binned =
        (unsigned long long*)(((size_t)(bucket_cur + 64) + 15) & ~(size_t)15);

    hipMemsetAsync(bufA, 0, (size_t)N * sizeof(int), stream);
    hipMemsetAsync(bucket_cnt, 0, 64 * sizeof(int), stream);

    k0_wt<<<128, 256, 0, stream>>>(lin_w, skip_w, wt);

    (void)hipFuncSetAttribute((const void*)k1_gemm,
                              hipFuncAttributeMaxDynamicSharedMemorySize, 81920);
    k1_gemm<<<(N + 63) / 64, 256, 81920, stream>>>(
        x, wt, att_src, att_dst, gat_bias, skip_b, xh_bf, asrc, adst, out, N);

    int nbe = (E + 4095) / 4096;
    kA_hist<<<nbe, 256, 0, stream>>>(ei, bufA, bucket_cnt, E);
    k_bscan<<<1, 64, 0, stream>>>(bucket_cnt, bucket_cur);

    int nb = (N + 255) / 256;
    k_scan1<<<nb, 256, 0, stream>>>(bufA, bsum, N);
    k_scan2<<<1, 512, 0, stream>>>(bsum, boff, nb);
    k_rp<<<nb, 256, 0, stream>>>(bufA, boff, cur, N);

    kB_bin<<<nbe, 256, 0, stream>>>(ei, bucket_cur, binned, E);
    kC_scatter<<<(E + 255) / 256, 256, 0, stream>>>(binned, cur, esrc, E);

    k3_agg<<<(N + 3) / 4, 256, 0, stream>>>(bufA, cur, esrc, asrc, adst,
                                            (const unsigned int*)xh_bf, out, N);
}

// Round 5
// 287.377 us; speedup vs baseline: 14.7267x; 1.1182x over previous
//
#include <hip/hip_runtime.h>
#include <math.h>

#define NEG 0.2f

typedef __attribute__((ext_vector_type(8))) short bf16x8;
typedef __attribute__((ext_vector_type(4))) float f32x4;

__device__ __forceinline__ unsigned short f2bf(float f) {
    unsigned u = __float_as_uint(f);
    u += 0x7fffu + ((u >> 16) & 1u);
    return (unsigned short)(u >> 16);
}
__device__ __forceinline__ float blo(unsigned v) { return __uint_as_float(v << 16); }
__device__ __forceinline__ float bhi(unsigned v) { return __uint_as_float(v & 0xffff0000u); }
__device__ __forceinline__ float lrexp(float v) {
    v = v > 0.f ? v : NEG * v;
    return __expf(v);
}

// ---------------------------------------------------------------------------
// K0: W^T precompute -> bf16  Wt[c][k] = W[k][c], c<128 lin, else skip
// ---------------------------------------------------------------------------
__global__ __launch_bounds__(256) void k0_wt(const float* __restrict__ lin_w,
                                             const float* __restrict__ skip_w,
                                             unsigned short* __restrict__ wt)
{
    int idx = blockIdx.x * 256 + threadIdx.x;   // 0..32767
    int k = idx >> 8, c = idx & 255;
    float v = (c < 128) ? lin_w[k * 128 + c] : skip_w[k * 128 + c - 128];
    wt[c * 128 + k] = f2bf(v);
}

// ---------------------------------------------------------------------------
// K1: bf16 MFMA GEMM  [64 rows, K=128] x [128, 256] per block. (unchanged R4)
// ---------------------------------------------------------------------------
__global__ __launch_bounds__(256, 2) void k1_gemm(
    const float* __restrict__ x, const unsigned short* __restrict__ wt,
    const float* __restrict__ att_src, const float* __restrict__ att_dst,
    const float* __restrict__ gat_bias, const float* __restrict__ skip_b,
    unsigned short* __restrict__ xh_bf, float* __restrict__ a_src,
    float* __restrict__ a_dst, float* __restrict__ out, int nrows)
{
    extern __shared__ char lds[];   // [0,16384) = A, [16384, 81920) = B
    const int t = threadIdx.x;
    const int row0 = blockIdx.x * 64;

#pragma unroll
    for (int q = 0; q < 16; ++q) {
        int c = q * 256 + t;
        int n = c >> 4, col8 = c & 15;
        uint4 v = *(const uint4*)(wt + n * 128 + col8 * 8);
        *(uint4*)(lds + 16384 + ((n * 256 + col8 * 16) ^ ((n & 7) << 4))) = v;
    }
#pragma unroll
    for (int q = 0; q < 4; ++q) {
        int c = q * 256 + t;
        int row = c >> 4, col8 = c & 15;
        float4 v0 = make_float4(0.f, 0.f, 0.f, 0.f), v1 = v0;
        if (row0 + row < nrows) {
            const float* gp = x + (size_t)(row0 + row) * 128 + col8 * 8;
            v0 = *(const float4*)gp;
            v1 = *(const float4*)(gp + 4);
        }
        bf16x8 b;
        b[0] = f2bf(v0.x); b[1] = f2bf(v0.y); b[2] = f2bf(v0.z); b[3] = f2bf(v0.w);
        b[4] = f2bf(v1.x); b[5] = f2bf(v1.y); b[6] = f2bf(v1.z); b[7] = f2bf(v1.w);
        *(bf16x8*)(lds + ((row * 256 + col8 * 16) ^ ((row & 7) << 4))) = b;
    }
    __syncthreads();

    const int w = t >> 6, l = t & 63, r = l & 15, half = l >> 4;
    f32x4 acc[16];
#pragma unroll
    for (int nt = 0; nt < 16; ++nt) acc[nt] = (f32x4){0.f, 0.f, 0.f, 0.f};

#pragma unroll
    for (int ks = 0; ks < 4; ++ks) {
        const int co = ks * 64 + half * 16;
        const int arow = w * 16 + r;
        bf16x8 a = *(const bf16x8*)(lds + ((arow * 256 + co) ^ ((r & 7) << 4)));
#pragma unroll
        for (int nt = 0; nt < 16; ++nt) {
            int n = nt * 16 + r;
            bf16x8 b = *(const bf16x8*)(lds + 16384 + ((n * 256 + co) ^ ((r & 7) << 4)));
            acc[nt] = __builtin_amdgcn_mfma_f32_16x16x32_bf16(a, b, acc[nt], 0, 0, 0);
        }
    }

#pragma unroll
    for (int nt = 0; nt < 8; ++nt) {
        float as_ = att_src[nt * 16 + r];
        float ad_ = att_dst[nt * 16 + r];
#pragma unroll
        for (int q = 0; q < 4; ++q) {
            int row = row0 + w * 16 + half * 4 + q;
            float v = acc[nt][q];
            float s = v * as_, d = v * ad_;
            s += __shfl_xor(s, 1, 16); d += __shfl_xor(d, 1, 16);
            s += __shfl_xor(s, 2, 16); d += __shfl_xor(d, 2, 16);
            s += __shfl_xor(s, 4, 16); d += __shfl_xor(d, 4, 16);
            s += __shfl_xor(s, 8, 16); d += __shfl_xor(d, 8, 16);
            if (row < nrows) {
                xh_bf[(size_t)row * 128 + nt * 16 + r] = f2bf(v);
                if (r == 0) {
                    a_src[(size_t)row * 8 + nt] = s;
                    a_dst[(size_t)row * 8 + nt] = d;
                }
            }
        }
    }
#pragma unroll
    for (int nt = 8; nt < 16; ++nt) {
        int c = (nt - 8) * 16 + r;
        float bb = gat_bias[c] + skip_b[c];
#pragma unroll
        for (int q = 0; q < 4; ++q) {
            int row = row0 + w * 16 + half * 4 + q;
            if (row < nrows) out[(size_t)row * 128 + c] = acc[nt][q] + bb;
        }
    }
}

// ---------------------------------------------------------------------------
// CSR build, R5: 256 buckets (dst>>9), LDS-cursor bucket sort.
// ---------------------------------------------------------------------------
__global__ __launch_bounds__(256) void kA_hist(const int* __restrict__ ei,
                                               int* __restrict__ node_cnt,
                                               int* __restrict__ bucket_cnt, int E)
{
    __shared__ int h[256];
    int t = threadIdx.x;
    h[t] = 0;
    __syncthreads();
    int eb = blockIdx.x * 4096;
#pragma unroll
    for (int u = 0; u < 16; ++u) {
        int e = eb + u * 256 + t;
        if (e < E) {
            int d = ei[E + e];
            atomicAdd(&node_cnt[d], 1);
            atomicAdd(&h[d >> 9], 1);
        }
    }
    __syncthreads();
    if (h[t]) atomicAdd(&bucket_cnt[t], h[t]);
}

__global__ __launch_bounds__(256) void k_bscan256(const int* __restrict__ bcnt,
                                                  int* __restrict__ bbase,
                                                  int* __restrict__ bcur)
{
    __shared__ int s[256];
    int t = threadIdx.x;
    int c = bcnt[t];
    s[t] = c;
    __syncthreads();
    for (int off = 1; off < 256; off <<= 1) {
        int a = (t >= off) ? s[t - off] : 0;
        __syncthreads();
        s[t] += a;
        __syncthreads();
    }
    int ex = s[t] - c;
    bbase[t] = ex;
    bcur[t] = ex;
}

__global__ __launch_bounds__(256) void kB_bin(const int* __restrict__ ei,
                                              int* __restrict__ bucket_cur,
                                              unsigned long long* __restrict__ binned,
                                              int E)
{
    __shared__ int h[256];
    __shared__ int base_[256];
    int t = threadIdx.x;
    h[t] = 0;
    __syncthreads();
    int eb = blockIdx.x * 4096;
    int srcv[16], dstv[16], rkv[16];
#pragma unroll
    for (int u = 0; u < 16; ++u) {
        int e = eb + u * 256 + t;
        srcv[u] = 0; dstv[u] = -1; rkv[u] = 0;
        if (e < E) {
            srcv[u] = ei[e];
            dstv[u] = ei[E + e];
            rkv[u] = atomicAdd(&h[dstv[u] >> 9], 1);
        }
    }
    __syncthreads();
    {
        int c = h[t];
        base_[t] = c ? atomicAdd(&bucket_cur[t], c) : 0;
    }
    __syncthreads();
#pragma unroll
    for (int u = 0; u < 16; ++u) {
        if (dstv[u] >= 0) {
            int b = dstv[u] >> 9;
            binned[base_[b] + rkv[u]] =
                ((unsigned long long)(unsigned)dstv[u] << 32) | (unsigned)srcv[u];
        }
    }
}

// one block per bucket: rank via LDS cursors, write esrc in a local window
__global__ __launch_bounds__(256) void kC_sort(
    const unsigned long long* __restrict__ binned,
    const int* __restrict__ bbase, const int* __restrict__ bcnt,
    const int* __restrict__ rowptr, int* __restrict__ esrc)
{
    __shared__ int cur[512];
    int t = threadIdx.x;
    cur[t] = 0; cur[t + 256] = 0;
    __syncthreads();
    int b = blockIdx.x;
    int base = bbase[b], cnt = bcnt[b];
    for (int e = t; e < cnt; e += 256) {
        unsigned long long p = binned[base + e];
        int d = (int)(p >> 32), s = (int)(p & 0xffffffffu);
        int slot = rowptr[d] + atomicAdd(&cur[d & 511], 1);
        esrc[slot] = s;
    }
}

// node-level scans: cnt preserved, rowptr separate
__global__ __launch_bounds__(256) void k_scan1(const int* __restrict__ cnt,
                                               int* __restrict__ pre,
                                               int* __restrict__ bsum, int n)
{
    __shared__ int s[256];
    int t = threadIdx.x, i = blockIdx.x * 256 + t;
    int v = (i < n) ? cnt[i] : 0;
    s[t] = v;
    __syncthreads();
    for (int off = 1; off < 256; off <<= 1) {
        int a = (t >= off) ? s[t - off] : 0;
        __syncthreads();
        s[t] += a;
        __syncthreads();
    }
    if (i < n) pre[i] = s[t] - v;
    if (t == 255) bsum[blockIdx.x] = s[255];
}

__global__ __launch_bounds__(512) void k_scan2(const int* __restrict__ bsum,
                                               int* __restrict__ boff, int nb)
{
    __shared__ int s[512];
    int t = threadIdx.x;
    int v = (t < nb) ? bsum[t] : 0;
    s[t] = v;
    __syncthreads();
    for (int off = 1; off < 512; off <<= 1) {
        int a = (t >= off) ? s[t - off] : 0;
        __syncthreads();
        s[t] += a;
        __syncthreads();
    }
    if (t < nb) boff[t] = s[t] - v;
}

__global__ __launch_bounds__(256) void k_rp(int* __restrict__ pre,
                                            const int* __restrict__ boff, int n)
{
    int i = blockIdx.x * 256 + threadIdx.x;
    if (i < n) pre[i] += boff[i >> 8];
}

// ---------------------------------------------------------------------------
// K3, R5: 32-bit indexing, unroll x8, exp-dedup via shfl.
// lane = h*8+u: computes exp for (edge k+u, head h); consumes via shfl.
// ---------------------------------------------------------------------------
__global__ __launch_bounds__(256) void k3_agg(
    const int* __restrict__ rowptr, const int* __restrict__ cntn,
    const int* __restrict__ esrc,
    const float* __restrict__ a_src, const float* __restrict__ a_dst,
    const unsigned int* __restrict__ xh32, float* __restrict__ out, int n)
{
    int i = blockIdx.x * 4 + (threadIdx.x >> 6);
    if (i >= n) return;
    const int lane = threadIdx.x & 63;
    const int h = lane >> 3, u = lane & 7;

    float adi = a_dst[(unsigned)i * 8 + h];
    float p0 = lrexp(a_src[(unsigned)i * 8 + h] + adi);
    unsigned uu = xh32[(unsigned)i * 64 + lane];
    float accx = p0 * blo(uu), accy = p0 * bhi(uu), den = p0;

    const int kbeg = rowptr[i], kend = kbeg + cntn[i];
    for (int k = kbeg; k < kend; k += 8) {
        // per-lane exp role: edge k+u, head h  (esrc padded by 8 zeros past E)
        int ke = k + u;
        int jm = esrc[ke];
        float pmv = lrexp(a_src[(unsigned)jm * 8 + h] + adi);
        float pm = (ke < kend) ? pmv : 0.f;

        // broadcast j's and issue all 8 gathers
        int j0 = esrc[k],     j1 = esrc[k + 1], j2 = esrc[k + 2], j3 = esrc[k + 3];
        int j4 = esrc[k + 4], j5 = esrc[k + 5], j6 = esrc[k + 6], j7 = esrc[k + 7];
        unsigned g0 = xh32[(unsigned)j0 * 64 + lane];
        unsigned g1 = xh32[(unsigned)j1 * 64 + lane];
        unsigned g2 = xh32[(unsigned)j2 * 64 + lane];
        unsigned g3 = xh32[(unsigned)j3 * 64 + lane];
        unsigned g4 = xh32[(unsigned)j4 * 64 + lane];
        unsigned g5 = xh32[(unsigned)j5 * 64 + lane];
        unsigned g6 = xh32[(unsigned)j6 * 64 + lane];
        unsigned g7 = xh32[(unsigned)j7 * 64 + lane];

        int sb = lane & 56;
        float p;
        p = __shfl(pm, sb | 0, 64); accx += p * blo(g0); accy += p * bhi(g0); den += p;
        p = __shfl(pm, sb | 1, 64); accx += p * blo(g1); accy += p * bhi(g1); den += p;
        p = __shfl(pm, sb | 2, 64); accx += p * blo(g2); accy += p * bhi(g2); den += p;
        p = __shfl(pm, sb | 3, 64); accx += p * blo(g3); accy += p * bhi(g3); den += p;
        p = __shfl(pm, sb | 4, 64); accx += p * blo(g4); accy += p * bhi(g4); den += p;
        p = __shfl(pm, sb | 5, 64); accx += p * blo(g5); accy += p * bhi(g5); den += p;
        p = __shfl(pm, sb | 6, 64); accx += p * blo(g6); accy += p * bhi(g6); den += p;
        p = __shfl(pm, sb | 7, 64); accx += p * blo(g7); accy += p * bhi(g7); den += p;
    }

    float inv = 1.f / (den + 1e-16f);
    unsigned o = (unsigned)i * 128 + lane * 2;
    float o0 = out[o]     + accx * inv;
    float o1 = out[o + 1] + accy * inv;
    o0 = o0 > 0.f ? o0 : __expf(o0) - 1.f;
    o1 = o1 > 0.f ? o1 : __expf(o1) - 1.f;
    out[o]     = o0;
    out[o + 1] = o1;
}

extern "C" void kernel_launch(void* const* d_in, const int* in_sizes, int n_in,
                              void* d_out, int out_size, void* d_ws, size_t ws_size,
                              hipStream_t stream)
{
    const float* x        = (const float*)d_in[0];
    const int*   ei       = (const int*)d_in[1];
    const float* lin_w    = (const float*)d_in[2];
    const float* att_src  = (const float*)d_in[3];
    const float* att_dst  = (const float*)d_in[4];
    const float* gat_bias = (const float*)d_in[5];
    const float* skip_w   = (const float*)d_in[6];
    const float* skip_b   = (const float*)d_in[7];
    float* out = (float*)d_out;

    const int N = in_sizes[0] / 128;
    const int E = in_sizes[1] / 2;

    float* ws   = (float*)d_ws;
    float* asrc = ws;                                   // N*8 f
    float* adst = asrc + (size_t)N * 8;                 // N*8 f
    unsigned short* wt    = (unsigned short*)(adst + (size_t)N * 8);  // 32768 bf16
    unsigned short* xh_bf = wt + 32768;                 // N*128 bf16
    int* cntn   = (int*)(xh_bf + (size_t)N * 128);      // N int
    int* rowptr = cntn + N;                             // N int
    int* esrc   = rowptr + N;                           // E+8 int (padded)
    int* bsum   = esrc + E + 8;                         // 512
    int* boff   = bsum + 512;                           // 512
    int* bcnt   = boff + 512;                           // 256
    int* bbase  = bcnt + 256;                           // 256
    int* bcur   = bbase + 256;                          // 256
    unsigned long long* binned =
        (unsigned long long*)(((size_t)(bcur + 256) + 15) & ~(size_t)15);

    hipMemsetAsync(cntn, 0, (size_t)N * sizeof(int), stream);
    hipMemsetAsync(bcnt, 0, 256 * sizeof(int), stream);
    hipMemsetAsync(esrc + E, 0, 8 * sizeof(int), stream);

    k0_wt<<<128, 256, 0, stream>>>(lin_w, skip_w, wt);

    (void)hipFuncSetAttribute((const void*)k1_gemm,
                              hipFuncAttributeMaxDynamicSharedMemorySize, 81920);
    k1_gemm<<<(N + 63) / 64, 256, 81920, stream>>>(
        x, wt, att_src, att_dst, gat_bias, skip_b, xh_bf, asrc, adst, out, N);

    int nbe = (E + 4095) / 4096;
    kA_hist<<<nbe, 256, 0, stream>>>(ei, cntn, bcnt, E);
    k_bscan256<<<1, 256, 0, stream>>>(bcnt, bbase, bcur);

    int nb = (N + 255) / 256;
    k_scan1<<<nb, 256, 0, stream>>>(cntn, rowptr, bsum, N);
    k_scan2<<<1, 512, 0, stream>>>(bsum, boff, nb);
    k_rp<<<nb, 256, 0, stream>>>(rowptr, boff, N);

    kB_bin<<<nbe, 256, 0, stream>>>(ei, bcur, binned, E);

    int nbk = (N + 511) >> 9;
    kC_sort<<<nbk, 256, 0, stream>>>(binned, bbase, bcnt, rowptr, esrc);

    k3_agg<<<(N + 3) / 4, 256, 0, stream>>>(rowptr, cntn, esrc, asrc, adst,
                                            (const unsigned int*)xh_bf, out, N);
}

// Round 6
// 271.935 us; speedup vs baseline: 15.5629x; 1.0568x over previous
//
#include <hip/hip_runtime.h>
#include <math.h>

#define NEG 0.2f

typedef __attribute__((ext_vector_type(8))) short bf16x8;
typedef __attribute__((ext_vector_type(4))) float f32x4;

__device__ __forceinline__ unsigned short f2bf(float f) {
    unsigned u = __float_as_uint(f);
    u += 0x7fffu + ((u >> 16) & 1u);
    return (unsigned short)(u >> 16);
}
__device__ __forceinline__ float blo(unsigned v) { return __uint_as_float(v << 16); }
__device__ __forceinline__ float bhi(unsigned v) { return __uint_as_float(v & 0xffff0000u); }
__device__ __forceinline__ float lrexp(float v) {
    v = v > 0.f ? v : NEG * v;
    return __expf(v);
}

// ---------------------------------------------------------------------------
// F1: [blocks 0..nba) = edge histogram (node cnt + bucket cnt)
//     [blocks nba..)  = MFMA GEMM tile (64 rows), B in registers per wave.
// wave w owns col-frags (heads) w*4..w*4+3; cols c=(w*4+cf)*16+r.
// ---------------------------------------------------------------------------
__global__ __launch_bounds__(256) void f1(
    const float* __restrict__ x, const float* __restrict__ lin_w,
    const float* __restrict__ skip_w, const float* __restrict__ att_src,
    const float* __restrict__ att_dst, const float* __restrict__ gat_bias,
    const float* __restrict__ skip_b, const int* __restrict__ ei,
    unsigned short* __restrict__ xh_bf, float* __restrict__ a_src,
    float* __restrict__ a_dst, float* __restrict__ out,
    int* __restrict__ cntn, int* __restrict__ bcnt,
    int nrows, int E, int nba, int nb)
{
    __shared__ __align__(16) char smem[16384];
    const int t = threadIdx.x;
    const int bid = blockIdx.x;

    if (bid < nba) {                      // ---- histogram role ----
        int* h = (int*)smem;
        h[t] = 0;
        __syncthreads();
        int eb = bid * 4096;
#pragma unroll
        for (int u = 0; u < 16; ++u) {
            int e = eb + u * 256 + t;
            if (e < E) {
                int d = ei[E + e];
                atomicAdd(&cntn[d], 1);
                atomicAdd(&h[d >> 9], 1);
            }
        }
        __syncthreads();
        if (t < nb && h[t]) atomicAdd(&bcnt[t], h[t]);
        return;
    }

    // ---- GEMM role ----
    const int row0 = (bid - nba) * 64;
    const int w = t >> 6, l = t & 63, r = l & 15, half = l >> 4;

    bf16x8 B[4][4];
    float atts[4], attd[4], bb[4];
#pragma unroll
    for (int cf = 0; cf < 4; ++cf) {
        const int c = (w * 4 + cf) * 16 + r;
        const float* wsrc = (c < 128) ? (lin_w + c) : (skip_w + c - 128);
#pragma unroll
        for (int ks = 0; ks < 4; ++ks) {
            bf16x8 bf;
#pragma unroll
            for (int i = 0; i < 8; ++i)
                bf[i] = (short)f2bf(wsrc[(ks * 32 + half * 8 + i) * 128]);
            B[cf][ks] = bf;
        }
        if (w < 2) { atts[cf] = att_src[c]; attd[cf] = att_dst[c]; bb[cf] = 0.f; }
        else       { atts[cf] = 0.f; attd[cf] = 0.f; bb[cf] = gat_bias[c - 128] + skip_b[c - 128]; }
    }

    // stage A tile [64][128] fp32 -> bf16 swizzled LDS (16 KB)
#pragma unroll
    for (int q = 0; q < 4; ++q) {
        int cslot = q * 256 + t;             // 0..1023 (16B slots)
        int row = cslot >> 4, col8 = cslot & 15;
        float4 v0 = make_float4(0.f, 0.f, 0.f, 0.f), v1 = v0;
        if (row0 + row < nrows) {
            const float* gp = x + (size_t)(row0 + row) * 128 + col8 * 8;
            v0 = *(const float4*)gp;
            v1 = *(const float4*)(gp + 4);
        }
        bf16x8 b;
        b[0] = f2bf(v0.x); b[1] = f2bf(v0.y); b[2] = f2bf(v0.z); b[3] = f2bf(v0.w);
        b[4] = f2bf(v1.x); b[5] = f2bf(v1.y); b[6] = f2bf(v1.z); b[7] = f2bf(v1.w);
        *(bf16x8*)(smem + ((row * 256 + col8 * 16) ^ ((row & 7) << 4))) = b;
    }
    __syncthreads();

    f32x4 acc[4][4];
#pragma unroll
    for (int rf = 0; rf < 4; ++rf)
#pragma unroll
        for (int cf = 0; cf < 4; ++cf) acc[rf][cf] = (f32x4){0.f, 0.f, 0.f, 0.f};

#pragma unroll
    for (int ks = 0; ks < 4; ++ks) {
        const int co = ks * 64 + half * 16;
#pragma unroll
        for (int rf = 0; rf < 4; ++rf) {
            const int arow = rf * 16 + r;
            bf16x8 a = *(const bf16x8*)(smem + ((arow * 256 + co) ^ ((r & 7) << 4)));
#pragma unroll
            for (int cf = 0; cf < 4; ++cf)
                acc[rf][cf] = __builtin_amdgcn_mfma_f32_16x16x32_bf16(a, B[cf][ks], acc[rf][cf], 0, 0, 0);
        }
    }

    if (w < 2) {                       // lin half: xh + attention coefficients
#pragma unroll
        for (int rf = 0; rf < 4; ++rf)
#pragma unroll
        for (int q = 0; q < 4; ++q) {
            int row = row0 + rf * 16 + half * 4 + q;
#pragma unroll
            for (int cf = 0; cf < 4; ++cf) {
                float v = acc[rf][cf][q];
                float s = v * atts[cf], d = v * attd[cf];
                s += __shfl_xor(s, 1, 16); d += __shfl_xor(d, 1, 16);
                s += __shfl_xor(s, 2, 16); d += __shfl_xor(d, 2, 16);
                s += __shfl_xor(s, 4, 16); d += __shfl_xor(d, 4, 16);
                s += __shfl_xor(s, 8, 16); d += __shfl_xor(d, 8, 16);
                if (row < nrows) {
                    xh_bf[(size_t)row * 128 + (w * 4 + cf) * 16 + r] = f2bf(v);
                    if (r == 0) {
                        a_src[(size_t)row * 8 + w * 4 + cf] = s;
                        a_dst[(size_t)row * 8 + w * 4 + cf] = d;
                    }
                }
            }
        }
    } else {                           // skip half: out = acc + biases
#pragma unroll
        for (int rf = 0; rf < 4; ++rf)
#pragma unroll
        for (int q = 0; q < 4; ++q) {
            int row = row0 + rf * 16 + half * 4 + q;
            if (row < nrows) {
#pragma unroll
                for (int cf = 0; cf < 4; ++cf) {
                    int c = (w * 4 + cf) * 16 + r - 128;
                    out[(size_t)row * 128 + c] = acc[rf][cf][q] + bb[cf];
                }
            }
        }
    }
}

// ---------------------------------------------------------------------------
// F2: every block LDS-scans bcnt -> bucket bases. Then:
//   [blocks 0..nb)   : per-bucket node scan -> rowptr, bbase_g
//   [blocks nb..)    : bin edges into (dst,src) u64 groups by bucket
// ---------------------------------------------------------------------------
__global__ __launch_bounds__(256) void f2(
    const int* __restrict__ ei, const int* __restrict__ cntn,
    const int* __restrict__ bcnt, int* __restrict__ rowptr,
    int* __restrict__ bbase_g, int* __restrict__ fill,
    unsigned long long* __restrict__ binned, int N, int E, int nb)
{
    __shared__ int bs[256];
    __shared__ int bexc[256];
    __shared__ int s1[256];
    __shared__ int s2[256];
    const int t = threadIdx.x;

    int c = (t < nb) ? bcnt[t] : 0;
    bs[t] = c;
    __syncthreads();
    for (int off = 1; off < 256; off <<= 1) {
        int a = (t >= off) ? bs[t - off] : 0;
        __syncthreads();
        bs[t] += a;
        __syncthreads();
    }
    bexc[t] = bs[t] - c;
    __syncthreads();

    if (blockIdx.x < (unsigned)nb) {       // ---- rowptr role ----
        int b = blockIdx.x;
        int base = bexc[b];
        int i0 = b * 512 + 2 * t, i1 = i0 + 1;
        int c0 = (i0 < N) ? cntn[i0] : 0;
        int c1 = (i1 < N) ? cntn[i1] : 0;
        int pv = c0 + c1;
        s1[t] = pv;
        __syncthreads();
        for (int off = 1; off < 256; off <<= 1) {
            int a = (t >= off) ? s1[t - off] : 0;
            __syncthreads();
            s1[t] += a;
            __syncthreads();
        }
        int ex = s1[t] - pv;
        if (i0 < N) rowptr[i0] = base + ex;
        if (i1 < N) rowptr[i1] = base + ex + c0;
        if (t == 0) bbase_g[b] = base;
        return;
    }

    // ---- binning role ----
    s1[t] = 0;                             // per-block bucket hist
    __syncthreads();
    int eb = (blockIdx.x - nb) * 4096;
    int srcv[16], dstv[16], rkv[16];
#pragma unroll
    for (int u = 0; u < 16; ++u) {
        int e = eb + u * 256 + t;
        srcv[u] = 0; dstv[u] = -1; rkv[u] = 0;
        if (e < E) {
            srcv[u] = ei[e];
            dstv[u] = ei[E + e];
            rkv[u] = atomicAdd(&s1[dstv[u] >> 9], 1);
        }
    }
    __syncthreads();
    {
        int hc = s1[t];
        s2[t] = bexc[t] + (hc ? atomicAdd(&fill[t], hc) : 0);
    }
    __syncthreads();
#pragma unroll
    for (int u = 0; u < 16; ++u) {
        if (dstv[u] >= 0) {
            int b = dstv[u] >> 9;
            binned[s2[b] + rkv[u]] =
                ((unsigned long long)(unsigned)dstv[u] << 32) | (unsigned)srcv[u];
        }
    }
}

// ---------------------------------------------------------------------------
// F3: per-bucket CSR scatter via LDS cursors (bucket = 512 nodes)
// ---------------------------------------------------------------------------
__global__ __launch_bounds__(256) void f3(
    const unsigned long long* __restrict__ binned,
    const int* __restrict__ bbase_g, const int* __restrict__ bcnt,
    const int* __restrict__ rowptr, int* __restrict__ esrc)
{
    __shared__ int cur[512];
    int t = threadIdx.x;
    cur[t] = 0; cur[t + 256] = 0;
    __syncthreads();
    int b = blockIdx.x;
    int base = bbase_g[b], cnt = bcnt[b];
    for (int e = t; e < cnt; e += 256) {
        unsigned long long p = binned[base + e];
        int d = (int)(p >> 32), s = (int)(p & 0xffffffffu);
        int slot = rowptr[d] + atomicAdd(&cur[d & 511], 1);
        esrc[slot] = s;
    }
}

// ---------------------------------------------------------------------------
// F4 = k3: fused denom + aggregation + skip + ELU (unchanged from R5)
// ---------------------------------------------------------------------------
__global__ __launch_bounds__(256) void k3_agg(
    const int* __restrict__ rowptr, const int* __restrict__ cntn,
    const int* __restrict__ esrc,
    const float* __restrict__ a_src, const float* __restrict__ a_dst,
    const unsigned int* __restrict__ xh32, float* __restrict__ out, int n)
{
    int i = blockIdx.x * 4 + (threadIdx.x >> 6);
    if (i >= n) return;
    const int lane = threadIdx.x & 63;
    const int h = lane >> 3, u = lane & 7;

    float adi = a_dst[(unsigned)i * 8 + h];
    float p0 = lrexp(a_src[(unsigned)i * 8 + h] + adi);
    unsigned uu = xh32[(unsigned)i * 64 + lane];
    float accx = p0 * blo(uu), accy = p0 * bhi(uu), den = p0;

    const int kbeg = rowptr[i], kend = kbeg + cntn[i];
    for (int k = kbeg; k < kend; k += 8) {
        int ke = k + u;
        int jm = esrc[ke];
        float pmv = lrexp(a_src[(unsigned)jm * 8 + h] + adi);
        float pm = (ke < kend) ? pmv : 0.f;

        int j0 = esrc[k],     j1 = esrc[k + 1], j2 = esrc[k + 2], j3 = esrc[k + 3];
        int j4 = esrc[k + 4], j5 = esrc[k + 5], j6 = esrc[k + 6], j7 = esrc[k + 7];
        unsigned g0 = xh32[(unsigned)j0 * 64 + lane];
        unsigned g1 = xh32[(unsigned)j1 * 64 + lane];
        unsigned g2 = xh32[(unsigned)j2 * 64 + lane];
        unsigned g3 = xh32[(unsigned)j3 * 64 + lane];
        unsigned g4 = xh32[(unsigned)j4 * 64 + lane];
        unsigned g5 = xh32[(unsigned)j5 * 64 + lane];
        unsigned g6 = xh32[(unsigned)j6 * 64 + lane];
        unsigned g7 = xh32[(unsigned)j7 * 64 + lane];

        int sb = lane & 56;
        float p;
        p = __shfl(pm, sb | 0, 64); accx += p * blo(g0); accy += p * bhi(g0); den += p;
        p = __shfl(pm, sb | 1, 64); accx += p * blo(g1); accy += p * bhi(g1); den += p;
        p = __shfl(pm, sb | 2, 64); accx += p * blo(g2); accy += p * bhi(g2); den += p;
        p = __shfl(pm, sb | 3, 64); accx += p * blo(g3); accy += p * bhi(g3); den += p;
        p = __shfl(pm, sb | 4, 64); accx += p * blo(g4); accy += p * bhi(g4); den += p;
        p = __shfl(pm, sb | 5, 64); accx += p * blo(g5); accy += p * bhi(g5); den += p;
        p = __shfl(pm, sb | 6, 64); accx += p * blo(g6); accy += p * bhi(g6); den += p;
        p = __shfl(pm, sb | 7, 64); accx += p * blo(g7); accy += p * bhi(g7); den += p;
    }

    float inv = 1.f / (den + 1e-16f);
    unsigned o = (unsigned)i * 128 + lane * 2;
    float o0 = out[o]     + accx * inv;
    float o1 = out[o + 1] + accy * inv;
    o0 = o0 > 0.f ? o0 : __expf(o0) - 1.f;
    o1 = o1 > 0.f ? o1 : __expf(o1) - 1.f;
    out[o]     = o0;
    out[o + 1] = o1;
}

extern "C" void kernel_launch(void* const* d_in, const int* in_sizes, int n_in,
                              void* d_out, int out_size, void* d_ws, size_t ws_size,
                              hipStream_t stream)
{
    const float* x        = (const float*)d_in[0];
    const int*   ei       = (const int*)d_in[1];
    const float* lin_w    = (const float*)d_in[2];
    const float* att_src  = (const float*)d_in[3];
    const float* att_dst  = (const float*)d_in[4];
    const float* gat_bias = (const float*)d_in[5];
    const float* skip_w   = (const float*)d_in[6];
    const float* skip_b   = (const float*)d_in[7];
    float* out = (float*)d_out;

    const int N = in_sizes[0] / 128;
    const int E = in_sizes[1] / 2;
    const int nb  = (N + 511) >> 9;            // buckets of 512 nodes (<=256)
    const int nba = (E + 4095) / 4096;         // edge blocks
    const int ntile = (N + 63) / 64;

    float* ws   = (float*)d_ws;
    float* asrc = ws;                                   // N*8 f
    float* adst = asrc + (size_t)N * 8;                 // N*8 f
    unsigned short* xh_bf = (unsigned short*)(adst + (size_t)N * 8);  // N*128 bf16
    int* cntn   = (int*)(xh_bf + (size_t)N * 128);      // N
    int* rowptr = cntn + N;                             // N
    int* esrc   = rowptr + N;                           // E+8 (padded)
    int* bcnt   = esrc + E + 8;                         // 256
    int* fill   = bcnt + 256;                           // 256
    int* bbase  = fill + 256;                           // 256
    unsigned long long* binned =
        (unsigned long long*)(((size_t)(bbase + 256) + 15) & ~(size_t)15);

    hipMemsetAsync(cntn, 0, (size_t)N * sizeof(int), stream);
    hipMemsetAsync(esrc + E, 0, (8 + 768) * sizeof(int), stream);  // pad + bcnt + fill + bbase

    f1<<<nba + ntile, 256, 0, stream>>>(
        x, lin_w, skip_w, att_src, att_dst, gat_bias, skip_b, ei,
        xh_bf, asrc, adst, out, cntn, bcnt, N, E, nba, nb);

    f2<<<nb + nba, 256, 0, stream>>>(ei, cntn, bcnt, rowptr, bbase, fill,
                                     binned, N, E, nb);

    f3<<<nb, 256, 0, stream>>>(binned, bbase, bcnt, rowptr, esrc);

    k3_agg<<<(N + 3) / 4, 256, 0, stream>>>(rowptr, cntn, esrc, asrc, adst,
                                            (const unsigned int*)xh_bf, out, N);
}

// Round 7
// 263.866 us; speedup vs baseline: 16.0389x; 1.0306x over previous
//
#include <hip/hip_runtime.h>
#include <math.h>

#define NEG 0.2f

typedef __attribute__((ext_vector_type(8))) short bf16x8;
typedef __attribute__((ext_vector_type(4))) float f32x4;

__device__ __forceinline__ unsigned short f2bf(float f) {
    unsigned u = __float_as_uint(f);
    u += 0x7fffu + ((u >> 16) & 1u);
    return (unsigned short)(u >> 16);
}
__device__ __forceinline__ float blo(unsigned v) { return __uint_as_float(v << 16); }
__device__ __forceinline__ float bhi(unsigned v) { return __uint_as_float(v & 0xffff0000u); }
__device__ __forceinline__ float lrexp(float v) {
    v = v > 0.f ? v : NEG * v;
    return __expf(v);
}

// ---------------------------------------------------------------------------
// K0: W^T precompute -> bf16  Wt[c][k] = W[k][c], c<128 lin, else skip
// ---------------------------------------------------------------------------
__global__ __launch_bounds__(256) void k0_wt(const float* __restrict__ lin_w,
                                             const float* __restrict__ skip_w,
                                             unsigned short* __restrict__ wt)
{
    int idx = blockIdx.x * 256 + threadIdx.x;   // 0..32767
    int k = idx >> 8, c = idx & 255;
    float v = (c < 128) ? lin_w[k * 128 + c] : skip_w[k * 128 + c - 128];
    wt[c * 128 + k] = f2bf(v);
}

// ---------------------------------------------------------------------------
// K1H: [blocks 0..nba) = edge histogram; [nba..) = MFMA GEMM, 128 rows/block
// (2 sub-tiles of 64 rows; B staged once in LDS, A re-staged per sub-tile).
// LDS: A 16 KB swizzled + B 64 KB swizzled.
// ---------------------------------------------------------------------------
__global__ __launch_bounds__(256, 2) void k1h(
    const float* __restrict__ x, const unsigned short* __restrict__ wt,
    const float* __restrict__ att_src, const float* __restrict__ att_dst,
    const float* __restrict__ gat_bias, const float* __restrict__ skip_b,
    const int* __restrict__ ei,
    unsigned short* __restrict__ xh_bf, float* __restrict__ a_src,
    float* __restrict__ a_dst, float* __restrict__ out,
    int* __restrict__ cntn, int* __restrict__ bcnt,
    int nrows, int E, int nba, int nb)
{
    extern __shared__ __align__(16) char lds[];   // [0,16K)=A, [16K,80K)=B
    const int t = threadIdx.x;
    const int bid = blockIdx.x;

    if (bid < nba) {                  // ---- histogram role ----
        int* h = (int*)lds;
        h[t] = 0;
        __syncthreads();
        int eb = bid * 4096;
#pragma unroll
        for (int u = 0; u < 16; ++u) {
            int e = eb + u * 256 + t;
            if (e < E) {
                int d = ei[E + e];
                atomicAdd(&cntn[d], 1);
                atomicAdd(&h[d >> 9], 1);
            }
        }
        __syncthreads();
        if (t < nb && h[t]) atomicAdd(&bcnt[t], h[t]);
        return;
    }

    // ---- GEMM role ----
    const int rowbase = (bid - nba) * 128;
    const int w = t >> 6, l = t & 63, r = l & 15, half = l >> 4;

    // stage B once: Wt [256][128] bf16 -> swizzled LDS
#pragma unroll
    for (int q = 0; q < 16; ++q) {
        int c = q * 256 + t;                 // 16B chunk id, 0..4095
        int n = c >> 4, col8 = c & 15;
        uint4 v = *(const uint4*)(wt + n * 128 + col8 * 8);
        *(uint4*)(lds + 16384 + ((n * 256 + col8 * 16) ^ ((n & 7) << 4))) = v;
    }

    for (int sub = 0; sub < 2; ++sub) {
        const int row0 = rowbase + sub * 64;
        if (sub) __syncthreads();            // protect A re-stage
        // stage A tile [64][128] fp32 -> bf16 swizzled LDS
#pragma unroll
        for (int q = 0; q < 4; ++q) {
            int cslot = q * 256 + t;         // 0..1023
            int row = cslot >> 4, col8 = cslot & 15;
            float4 v0 = make_float4(0.f, 0.f, 0.f, 0.f), v1 = v0;
            if (row0 + row < nrows) {
                const float* gp = x + (size_t)(row0 + row) * 128 + col8 * 8;
                v0 = *(const float4*)gp;
                v1 = *(const float4*)(gp + 4);
            }
            bf16x8 b;
            b[0] = f2bf(v0.x); b[1] = f2bf(v0.y); b[2] = f2bf(v0.z); b[3] = f2bf(v0.w);
            b[4] = f2bf(v1.x); b[5] = f2bf(v1.y); b[6] = f2bf(v1.z); b[7] = f2bf(v1.w);
            *(bf16x8*)(lds + ((row * 256 + col8 * 16) ^ ((row & 7) << 4))) = b;
        }
        __syncthreads();

        f32x4 acc[16];
#pragma unroll
        for (int nt = 0; nt < 16; ++nt) acc[nt] = (f32x4){0.f, 0.f, 0.f, 0.f};

#pragma unroll
        for (int ks = 0; ks < 4; ++ks) {
            const int co = ks * 64 + half * 16;
            const int arow = w * 16 + r;
            bf16x8 a = *(const bf16x8*)(lds + ((arow * 256 + co) ^ ((r & 7) << 4)));
#pragma unroll
            for (int nt = 0; nt < 16; ++nt) {
                int n = nt * 16 + r;
                bf16x8 b = *(const bf16x8*)(lds + 16384 + ((n * 256 + co) ^ ((r & 7) << 4)));
                acc[nt] = __builtin_amdgcn_mfma_f32_16x16x32_bf16(a, b, acc[nt], 0, 0, 0);
            }
        }

        // epilogue — lin half: xh + attention coefficients
#pragma unroll
        for (int nt = 0; nt < 8; ++nt) {
            float as_ = att_src[nt * 16 + r];
            float ad_ = att_dst[nt * 16 + r];
#pragma unroll
            for (int q = 0; q < 4; ++q) {
                int row = row0 + w * 16 + half * 4 + q;
                float v = acc[nt][q];
                float s = v * as_, d = v * ad_;
                s += __shfl_xor(s, 1, 16); d += __shfl_xor(d, 1, 16);
                s += __shfl_xor(s, 2, 16); d += __shfl_xor(d, 2, 16);
                s += __shfl_xor(s, 4, 16); d += __shfl_xor(d, 4, 16);
                s += __shfl_xor(s, 8, 16); d += __shfl_xor(d, 8, 16);
                if (row < nrows) {
                    xh_bf[(size_t)row * 128 + nt * 16 + r] = f2bf(v);
                    if (r == 0) {
                        a_src[(size_t)row * 8 + nt] = s;
                        a_dst[(size_t)row * 8 + nt] = d;
                    }
                }
            }
        }
        // skip half: out = acc + biases
#pragma unroll
        for (int nt = 8; nt < 16; ++nt) {
            int c = (nt - 8) * 16 + r;
            float bb = gat_bias[c] + skip_b[c];
#pragma unroll
            for (int q = 0; q < 4; ++q) {
                int row = row0 + w * 16 + half * 4 + q;
                if (row < nrows) out[(size_t)row * 128 + c] = acc[nt][q] + bb;
            }
        }
    }
}

// ---------------------------------------------------------------------------
// F2: every block LDS-scans bcnt -> bucket bases. Then:
//   [blocks 0..nb) : per-bucket node scan -> rowptr, bbase_g
//   [blocks nb..)  : bin edges into (dst,src) u64 groups by bucket
// ---------------------------------------------------------------------------
__global__ __launch_bounds__(256) void f2(
    const int* __restrict__ ei, const int* __restrict__ cntn,
    const int* __restrict__ bcnt, int* __restrict__ rowptr,
    int* __restrict__ bbase_g, int* __restrict__ fill,
    unsigned long long* __restrict__ binned, int N, int E, int nb)
{
    __shared__ int bs[256];
    __shared__ int bexc[256];
    __shared__ int s1[256];
    __shared__ int s2[256];
    const int t = threadIdx.x;

    int c = (t < nb) ? bcnt[t] : 0;
    bs[t] = c;
    __syncthreads();
    for (int off = 1; off < 256; off <<= 1) {
        int a = (t >= off) ? bs[t - off] : 0;
        __syncthreads();
        bs[t] += a;
        __syncthreads();
    }
    bexc[t] = bs[t] - c;
    __syncthreads();

    if (blockIdx.x < (unsigned)nb) {       // ---- rowptr role ----
        int b = blockIdx.x;
        int base = bexc[b];
        int i0 = b * 512 + 2 * t, i1 = i0 + 1;
        int c0 = (i0 < N) ? cntn[i0] : 0;
        int c1 = (i1 < N) ? cntn[i1] : 0;
        int pv = c0 + c1;
        s1[t] = pv;
        __syncthreads();
        for (int off = 1; off < 256; off <<= 1) {
            int a = (t >= off) ? s1[t - off] : 0;
            __syncthreads();
            s1[t] += a;
            __syncthreads();
        }
        int ex = s1[t] - pv;
        if (i0 < N) rowptr[i0] = base + ex;
        if (i1 < N) rowptr[i1] = base + ex + c0;
        if (t == 0) bbase_g[b] = base;
        return;
    }

    // ---- binning role ----
    s1[t] = 0;
    __syncthreads();
    int eb = (blockIdx.x - nb) * 4096;
    int srcv[16], dstv[16], rkv[16];
#pragma unroll
    for (int u = 0; u < 16; ++u) {
        int e = eb + u * 256 + t;
        srcv[u] = 0; dstv[u] = -1; rkv[u] = 0;
        if (e < E) {
            srcv[u] = ei[e];
            dstv[u] = ei[E + e];
            rkv[u] = atomicAdd(&s1[dstv[u] >> 9], 1);
        }
    }
    __syncthreads();
    {
        int hc = s1[t];
        s2[t] = bexc[t] + (hc ? atomicAdd(&fill[t], hc) : 0);
    }
    __syncthreads();
#pragma unroll
    for (int u = 0; u < 16; ++u) {
        if (dstv[u] >= 0) {
            int b = dstv[u] >> 9;
            binned[s2[b] + rkv[u]] =
                ((unsigned long long)(unsigned)dstv[u] << 32) | (unsigned)srcv[u];
        }
    }
}

// ---------------------------------------------------------------------------
// F3: per-bucket CSR scatter via LDS cursors (bucket = 512 nodes)
// ---------------------------------------------------------------------------
__global__ __launch_bounds__(256) void f3(
    const unsigned long long* __restrict__ binned,
    const int* __restrict__ bbase_g, const int* __restrict__ bcnt,
    const int* __restrict__ rowptr, int* __restrict__ esrc)
{
    __shared__ int cur[512];
    int t = threadIdx.x;
    cur[t] = 0; cur[t + 256] = 0;
    __syncthreads();
    int b = blockIdx.x;
    int base = bbase_g[b], cnt = bcnt[b];
    for (int e = t; e < cnt; e += 256) {
        unsigned long long p = binned[base + e];
        int d = (int)(p >> 32), s = (int)(p & 0xffffffffu);
        int slot = rowptr[d] + atomicAdd(&cur[d & 511], 1);
        esrc[slot] = s;
    }
}

// ---------------------------------------------------------------------------
// K3: fused denom + aggregation + skip + ELU (unchanged — at gather roofline)
// ---------------------------------------------------------------------------
__global__ __launch_bounds__(256) void k3_agg(
    const int* __restrict__ rowptr, const int* __restrict__ cntn,
    const int* __restrict__ esrc,
    const float* __restrict__ a_src, const float* __restrict__ a_dst,
    const unsigned int* __restrict__ xh32, float* __restrict__ out, int n)
{
    int i = blockIdx.x * 4 + (threadIdx.x >> 6);
    if (i >= n) return;
    const int lane = threadIdx.x & 63;
    const int h = lane >> 3, u = lane & 7;

    float adi = a_dst[(unsigned)i * 8 + h];
    float p0 = lrexp(a_src[(unsigned)i * 8 + h] + adi);
    unsigned uu = xh32[(unsigned)i * 64 + lane];
    float accx = p0 * blo(uu), accy = p0 * bhi(uu), den = p0;

    const int kbeg = rowptr[i], kend = kbeg + cntn[i];
    for (int k = kbeg; k < kend; k += 8) {
        int ke = k + u;
        int jm = esrc[ke];
        float pmv = lrexp(a_src[(unsigned)jm * 8 + h] + adi);
        float pm = (ke < kend) ? pmv : 0.f;

        int j0 = esrc[k],     j1 = esrc[k + 1], j2 = esrc[k + 2], j3 = esrc[k + 3];
        int j4 = esrc[k + 4], j5 = esrc[k + 5], j6 = esrc[k + 6], j7 = esrc[k + 7];
        unsigned g0 = xh32[(unsigned)j0 * 64 + lane];
        unsigned g1 = xh32[(unsigned)j1 * 64 + lane];
        unsigned g2 = xh32[(unsigned)j2 * 64 + lane];
        unsigned g3 = xh32[(unsigned)j3 * 64 + lane];
        unsigned g4 = xh32[(unsigned)j4 * 64 + lane];
        unsigned g5 = xh32[(unsigned)j5 * 64 + lane];
        unsigned g6 = xh32[(unsigned)j6 * 64 + lane];
        unsigned g7 = xh32[(unsigned)j7 * 64 + lane];

        int sb = lane & 56;
        float p;
        p = __shfl(pm, sb | 0, 64); accx += p * blo(g0); accy += p * bhi(g0); den += p;
        p = __shfl(pm, sb | 1, 64); accx += p * blo(g1); accy += p * bhi(g1); den += p;
        p = __shfl(pm, sb | 2, 64); accx += p * blo(g2); accy += p * bhi(g2); den += p;
        p = __shfl(pm, sb | 3, 64); accx += p * blo(g3); accy += p * bhi(g3); den += p;
        p = __shfl(pm, sb | 4, 64); accx += p * blo(g4); accy += p * bhi(g4); den += p;
        p = __shfl(pm, sb | 5, 64); accx += p * blo(g5); accy += p * bhi(g5); den += p;
        p = __shfl(pm, sb | 6, 64); accx += p * blo(g6); accy += p * bhi(g6); den += p;
        p = __shfl(pm, sb | 7, 64); accx += p * blo(g7); accy += p * bhi(g7); den += p;
    }

    float inv = 1.f / (den + 1e-16f);
    unsigned o = (unsigned)i * 128 + lane * 2;
    float o0 = out[o]     + accx * inv;
    float o1 = out[o + 1] + accy * inv;
    o0 = o0 > 0.f ? o0 : __expf(o0) - 1.f;
    o1 = o1 > 0.f ? o1 : __expf(o1) - 1.f;
    out[o]     = o0;
    out[o + 1] = o1;
}

extern "C" void kernel_launch(void* const* d_in, const int* in_sizes, int n_in,
                              void* d_out, int out_size, void* d_ws, size_t ws_size,
                              hipStream_t stream)
{
    const float* x        = (const float*)d_in[0];
    const int*   ei       = (const int*)d_in[1];
    const float* lin_w    = (const float*)d_in[2];
    const float* att_src  = (const float*)d_in[3];
    const float* att_dst  = (const float*)d_in[4];
    const float* gat_bias = (const float*)d_in[5];
    const float* skip_w   = (const float*)d_in[6];
    const float* skip_b   = (const float*)d_in[7];
    float* out = (float*)d_out;

    const int N = in_sizes[0] / 128;
    const int E = in_sizes[1] / 2;
    const int nb  = (N + 511) >> 9;            // buckets of 512 nodes (<=256)
    const int nba = (E + 4095) / 4096;         // edge blocks
    const int ntile2 = (N + 127) / 128;        // 128-row GEMM tiles

    float* ws   = (float*)d_ws;
    float* asrc = ws;                                   // N*8 f
    float* adst = asrc + (size_t)N * 8;                 // N*8 f
    unsigned short* wt = (unsigned short*)(adst + (size_t)N * 8);     // 32768 bf16
    unsigned short* xh_bf = wt + 32768;                 // N*128 bf16
    int* cntn   = (int*)(xh_bf + (size_t)N * 128);      // N
    int* rowptr = cntn + N;                             // N
    int* esrc   = rowptr + N;                           // E+8 (padded)
    int* bcnt   = esrc + E + 8;                         // 256
    int* fill   = bcnt + 256;                           // 256
    int* bbase  = fill + 256;                           // 256
    unsigned long long* binned =
        (unsigned long long*)(((size_t)(bbase + 256) + 15) & ~(size_t)15);

    hipMemsetAsync(cntn, 0, (size_t)N * sizeof(int), stream);
    hipMemsetAsync(esrc + E, 0, (8 + 768) * sizeof(int), stream);  // pad+bcnt+fill+bbase

    k0_wt<<<128, 256, 0, stream>>>(lin_w, skip_w, wt);

    (void)hipFuncSetAttribute((const void*)k1h,
                              hipFuncAttributeMaxDynamicSharedMemorySize, 81920);
    k1h<<<nba + ntile2, 256, 81920, stream>>>(
        x, wt, att_src, att_dst, gat_bias, skip_b, ei,
        xh_bf, asrc, adst, out, cntn, bcnt, N, E, nba, nb);

    f2<<<nb + nba, 256, 0, stream>>>(ei, cntn, bcnt, rowptr, bbase, fill,
                                     binned, N, E, nb);

    f3<<<nb, 256, 0, stream>>>(binned, bbase, bcnt, rowptr, esrc);

    k3_agg<<<(N + 3) / 4, 256, 0, stream>>>(rowptr, cntn, esrc, asrc, adst,
                                            (const unsigned int*)xh_bf, out, N);
}

// Round 8
// 244.726 us; speedup vs baseline: 17.2933x; 1.0782x over previous
//
#include <hip/hip_runtime.h>
#include <math.h>

#define NEG 0.2f

typedef __attribute__((ext_vector_type(8))) short bf16x8;
typedef __attribute__((ext_vector_type(4))) float f32x4;

__device__ __forceinline__ unsigned short f2bf(float f) {
    unsigned u = __float_as_uint(f);
    u += 0x7fffu + ((u >> 16) & 1u);
    return (unsigned short)(u >> 16);
}
__device__ __forceinline__ float blo(unsigned v) { return __uint_as_float(v << 16); }
__device__ __forceinline__ float bhi(unsigned v) { return __uint_as_float(v & 0xffff0000u); }
__device__ __forceinline__ float lrexp(float v) {
    v = v > 0.f ? v : NEG * v;
    return __expf(v);
}

// ---------------------------------------------------------------------------
// K0: W^T precompute -> bf16  Wt[c][k] = W[k][c], c<128 lin, else skip
// ---------------------------------------------------------------------------
__global__ __launch_bounds__(256) void k0_wt(const float* __restrict__ lin_w,
                                             const float* __restrict__ skip_w,
                                             unsigned short* __restrict__ wt)
{
    int idx = blockIdx.x * 256 + threadIdx.x;   // 0..32767
    int k = idx >> 8, c = idx & 255;
    float v = (c < 128) ? lin_w[k * 128 + c] : skip_w[k * 128 + c - 128];
    wt[c * 128 + k] = f2bf(v);
}

// ---------------------------------------------------------------------------
// K1: MFMA GEMM, 4x4 register blocking (m97 recipe).
// Block tile 128 rows x 128 cols (grid = rowblocks x 2 colblocks).
// Wave tile 64x64: per ks, 4 A-frag + 4 B-frag ds_reads feed 16 MFMA.
// LDS: A 32 KB + B 32 KB, both XOR-swizzled.
// ---------------------------------------------------------------------------
__global__ __launch_bounds__(256, 2) void k1_gemm(
    const float* __restrict__ x, const unsigned short* __restrict__ wt,
    const float* __restrict__ att_src, const float* __restrict__ att_dst,
    const float* __restrict__ gat_bias, const float* __restrict__ skip_b,
    unsigned short* __restrict__ xh_bf, float* __restrict__ a_src,
    float* __restrict__ a_dst, float* __restrict__ out, int nrows)
{
    extern __shared__ __align__(16) char lds[];   // [0,32K)=A, [32K,64K)=B
    const int t = threadIdx.x;
    const int rb = blockIdx.x >> 1, cb = blockIdx.x & 1;
    const int row0 = rb * 128;

    // stage B: wt rows cb*128..+127 -> [128][128] bf16 swizzled
#pragma unroll
    for (int q = 0; q < 8; ++q) {
        int slot = q * 256 + t;              // 0..2047 16B slots
        int c = slot >> 4, col8 = slot & 15;
        uint4 v = *(const uint4*)(wt + (size_t)(cb * 128 + c) * 128 + col8 * 8);
        *(uint4*)(lds + 32768 + ((c * 256 + col8 * 16) ^ ((c & 7) << 4))) = v;
    }
    // stage A: x[row0..row0+128) fp32 -> bf16 swizzled
#pragma unroll
    for (int q = 0; q < 8; ++q) {
        int slot = q * 256 + t;              // 0..2047
        int row = slot >> 4, col8 = slot & 15;
        float4 v0 = make_float4(0.f, 0.f, 0.f, 0.f), v1 = v0;
        if (row0 + row < nrows) {
            const float* gp = x + (size_t)(row0 + row) * 128 + col8 * 8;
            v0 = *(const float4*)gp;
            v1 = *(const float4*)(gp + 4);
        }
        bf16x8 b;
        b[0] = f2bf(v0.x); b[1] = f2bf(v0.y); b[2] = f2bf(v0.z); b[3] = f2bf(v0.w);
        b[4] = f2bf(v1.x); b[5] = f2bf(v1.y); b[6] = f2bf(v1.z); b[7] = f2bf(v1.w);
        *(bf16x8*)(lds + ((row * 256 + col8 * 16) ^ ((row & 7) << 4))) = b;
    }
    __syncthreads();

    const int w = t >> 6, l = t & 63, r = l & 15, half = l >> 4;
    const int wr = w >> 1, wc = w & 1;       // wave tile: rows wr*64, cols wc*64

    f32x4 acc[4][4];
#pragma unroll
    for (int rf = 0; rf < 4; ++rf)
#pragma unroll
        for (int cf = 0; cf < 4; ++cf) acc[rf][cf] = (f32x4){0.f, 0.f, 0.f, 0.f};

#pragma unroll
    for (int ks = 0; ks < 4; ++ks) {
        const int co = ks * 64 + half * 16;
        bf16x8 aF[4], bF[4];
#pragma unroll
        for (int rf = 0; rf < 4; ++rf) {
            int arow = wr * 64 + rf * 16 + r;
            aF[rf] = *(const bf16x8*)(lds + ((arow * 256 + co) ^ ((arow & 7) << 4)));
        }
#pragma unroll
        for (int cf = 0; cf < 4; ++cf) {
            int bcol = wc * 64 + cf * 16 + r;
            bF[cf] = *(const bf16x8*)(lds + 32768 + ((bcol * 256 + co) ^ ((bcol & 7) << 4)));
        }
#pragma unroll
        for (int rf = 0; rf < 4; ++rf)
#pragma unroll
            for (int cf = 0; cf < 4; ++cf)
                acc[rf][cf] = __builtin_amdgcn_mfma_f32_16x16x32_bf16(aF[rf], bF[cf], acc[rf][cf], 0, 0, 0);
    }

    if (cb == 0) {      // lin half: xh + attention coefficients
#pragma unroll
        for (int cf = 0; cf < 4; ++cf) {
            int clocal = wc * 64 + cf * 16 + r;
            float as_ = att_src[clocal], ad_ = att_dst[clocal];
            int head = wc * 4 + cf;
#pragma unroll
            for (int rf = 0; rf < 4; ++rf)
#pragma unroll
            for (int q = 0; q < 4; ++q) {
                int row = row0 + wr * 64 + rf * 16 + half * 4 + q;
                float v = acc[rf][cf][q];
                float s = v * as_, d = v * ad_;
                s += __shfl_xor(s, 1, 16); d += __shfl_xor(d, 1, 16);
                s += __shfl_xor(s, 2, 16); d += __shfl_xor(d, 2, 16);
                s += __shfl_xor(s, 4, 16); d += __shfl_xor(d, 4, 16);
                s += __shfl_xor(s, 8, 16); d += __shfl_xor(d, 8, 16);
                if (row < nrows) {
                    xh_bf[(size_t)row * 128 + clocal] = f2bf(v);
                    if (r == 0) {
                        a_src[(size_t)row * 8 + head] = s;
                        a_dst[(size_t)row * 8 + head] = d;
                    }
                }
            }
        }
    } else {            // skip half: out = acc + biases
#pragma unroll
        for (int cf = 0; cf < 4; ++cf) {
            int clocal = wc * 64 + cf * 16 + r;
            float bb = gat_bias[clocal] + skip_b[clocal];
#pragma unroll
            for (int rf = 0; rf < 4; ++rf)
#pragma unroll
            for (int q = 0; q < 4; ++q) {
                int row = row0 + wr * 64 + rf * 16 + half * 4 + q;
                if (row < nrows)
                    out[(size_t)row * 128 + clocal] = acc[rf][cf][q] + bb;
            }
        }
    }
}

// ---------------------------------------------------------------------------
// kA: bucket counts only (LDS histogram, no per-node global atomics)
// ---------------------------------------------------------------------------
__global__ __launch_bounds__(256) void kA_hist(const int* __restrict__ ei,
                                               int* __restrict__ bcnt,
                                               int E, int nb)
{
    __shared__ int h[256];
    int t = threadIdx.x;
    h[t] = 0;
    __syncthreads();
    int eb = blockIdx.x * 4096;
#pragma unroll
    for (int u = 0; u < 16; ++u) {
        int e = eb + u * 256 + t;
        if (e < E) atomicAdd(&h[ei[E + e] >> 9], 1);
    }
    __syncthreads();
    if (t < nb && h[t]) atomicAdd(&bcnt[t], h[t]);
}

// ---------------------------------------------------------------------------
// F2: every block LDS-scans bcnt -> bucket bases; bins edges into (dst,src)
// u64 bucket-grouped array.
// ---------------------------------------------------------------------------
__global__ __launch_bounds__(256) void f2(
    const int* __restrict__ ei, const int* __restrict__ bcnt,
    int* __restrict__ fill, unsigned long long* __restrict__ binned,
    int E, int nb)
{
    __shared__ int bs[256];
    __shared__ int bexc[256];
    __shared__ int s1[256];
    __shared__ int s2[256];
    const int t = threadIdx.x;

    int c = (t < nb) ? bcnt[t] : 0;
    bs[t] = c;
    __syncthreads();
    for (int off = 1; off < 256; off <<= 1) {
        int a = (t >= off) ? bs[t - off] : 0;
        __syncthreads();
        bs[t] += a;
        __syncthreads();
    }
    bexc[t] = bs[t] - c;
    __syncthreads();

    s1[t] = 0;
    __syncthreads();
    int eb = blockIdx.x * 4096;
    int srcv[16], dstv[16], rkv[16];
#pragma unroll
    for (int u = 0; u < 16; ++u) {
        int e = eb + u * 256 + t;
        srcv[u] = 0; dstv[u] = -1; rkv[u] = 0;
        if (e < E) {
            srcv[u] = ei[e];
            dstv[u] = ei[E + e];
            rkv[u] = atomicAdd(&s1[dstv[u] >> 9], 1);
        }
    }
    __syncthreads();
    {
        int hc = s1[t];
        s2[t] = bexc[t] + (hc ? atomicAdd(&fill[t], hc) : 0);
    }
    __syncthreads();
#pragma unroll
    for (int u = 0; u < 16; ++u) {
        if (dstv[u] >= 0) {
            int b = dstv[u] >> 9;
            binned[s2[b] + rkv[u]] =
                ((unsigned long long)(unsigned)dstv[u] << 32) | (unsigned)srcv[u];
        }
    }
}

// ---------------------------------------------------------------------------
// F3: one block per bucket (512 nodes). Count bucket nodes in LDS, local
// scan -> rowptr/cntn, then CSR-scatter esrc via LDS cursors.
// ---------------------------------------------------------------------------
__global__ __launch_bounds__(256) void f3(
    const unsigned long long* __restrict__ binned,
    const int* __restrict__ bcnt,
    int* __restrict__ rowptr, int* __restrict__ cntn,
    int* __restrict__ esrc, int N, int nb)
{
    __shared__ int bs[256];
    __shared__ int h[512];
    __shared__ int sc[256];
    const int t = threadIdx.x;
    const int b = blockIdx.x;

    // bucket base via LDS scan of bcnt
    int c = (t < nb) ? bcnt[t] : 0;
    bs[t] = c;
    __syncthreads();
    for (int off = 1; off < 256; off <<= 1) {
        int a = (t >= off) ? bs[t - off] : 0;
        __syncthreads();
        bs[t] += a;
        __syncthreads();
    }
    const int base = bs[b] - bcnt[b];
    const int cnt = bcnt[b];

    h[t] = 0; h[t + 256] = 0;
    __syncthreads();
    // pass 1: per-node counts
    for (int e = t; e < cnt; e += 256) {
        int d = (int)(binned[base + e] >> 32);
        atomicAdd(&h[d & 511], 1);
    }
    __syncthreads();
    // local scan of 512 counts (2 per thread)
    int i0 = 2 * t, i1 = i0 + 1;
    int c0 = h[i0], c1 = h[i1], pv = c0 + c1;
    sc[t] = pv;
    __syncthreads();
    for (int off = 1; off < 256; off <<= 1) {
        int a = (t >= off) ? sc[t - off] : 0;
        __syncthreads();
        sc[t] += a;
        __syncthreads();
    }
    int ex = sc[t] - pv;
    int n0 = b * 512 + i0;
    if (n0 < N)     { rowptr[n0]     = base + ex;      cntn[n0]     = c0; }
    if (n0 + 1 < N) { rowptr[n0 + 1] = base + ex + c0; cntn[n0 + 1] = c1; }
    h[i0] = base + ex;
    h[i1] = base + ex + c0;
    __syncthreads();
    // pass 2: scatter
    for (int e = t; e < cnt; e += 256) {
        unsigned long long p = binned[base + e];
        int d = (int)(p >> 32), s = (int)(p & 0xffffffffu);
        int slot = atomicAdd(&h[d & 511], 1);
        esrc[slot] = s;
    }
}

// ---------------------------------------------------------------------------
// K3: fused denom + aggregation + skip + ELU (unchanged — at gather roofline)
// ---------------------------------------------------------------------------
__global__ __launch_bounds__(256) void k3_agg(
    const int* __restrict__ rowptr, const int* __restrict__ cntn,
    const int* __restrict__ esrc,
    const float* __restrict__ a_src, const float* __restrict__ a_dst,
    const unsigned int* __restrict__ xh32, float* __restrict__ out, int n)
{
    int i = blockIdx.x * 4 + (threadIdx.x >> 6);
    if (i >= n) return;
    const int lane = threadIdx.x & 63;
    const int h = lane >> 3, u = lane & 7;

    float adi = a_dst[(unsigned)i * 8 + h];
    float p0 = lrexp(a_src[(unsigned)i * 8 + h] + adi);
    unsigned uu = xh32[(unsigned)i * 64 + lane];
    float accx = p0 * blo(uu), accy = p0 * bhi(uu), den = p0;

    const int kbeg = rowptr[i], kend = kbeg + cntn[i];
    for (int k = kbeg; k < kend; k += 8) {
        int ke = k + u;
        int jm = esrc[ke];
        float pmv = lrexp(a_src[(unsigned)jm * 8 + h] + adi);
        float pm = (ke < kend) ? pmv : 0.f;

        int j0 = esrc[k],     j1 = esrc[k + 1], j2 = esrc[k + 2], j3 = esrc[k + 3];
        int j4 = esrc[k + 4], j5 = esrc[k + 5], j6 = esrc[k + 6], j7 = esrc[k + 7];
        unsigned g0 = xh32[(unsigned)j0 * 64 + lane];
        unsigned g1 = xh32[(unsigned)j1 * 64 + lane];
        unsigned g2 = xh32[(unsigned)j2 * 64 + lane];
        unsigned g3 = xh32[(unsigned)j3 * 64 + lane];
        unsigned g4 = xh32[(unsigned)j4 * 64 + lane];
        unsigned g5 = xh32[(unsigned)j5 * 64 + lane];
        unsigned g6 = xh32[(unsigned)j6 * 64 + lane];
        unsigned g7 = xh32[(unsigned)j7 * 64 + lane];

        int sb = lane & 56;
        float p;
        p = __shfl(pm, sb | 0, 64); accx += p * blo(g0); accy += p * bhi(g0); den += p;
        p = __shfl(pm, sb | 1, 64); accx += p * blo(g1); accy += p * bhi(g1); den += p;
        p = __shfl(pm, sb | 2, 64); accx += p * blo(g2); accy += p * bhi(g2); den += p;
        p = __shfl(pm, sb | 3, 64); accx += p * blo(g3); accy += p * bhi(g3); den += p;
        p = __shfl(pm, sb | 4, 64); accx += p * blo(g4); accy += p * bhi(g4); den += p;
        p = __shfl(pm, sb | 5, 64); accx += p * blo(g5); accy += p * bhi(g5); den += p;
        p = __shfl(pm, sb | 6, 64); accx += p * blo(g6); accy += p * bhi(g6); den += p;
        p = __shfl(pm, sb | 7, 64); accx += p * blo(g7); accy += p * bhi(g7); den += p;
    }

    float inv = 1.f / (den + 1e-16f);
    unsigned o = (unsigned)i * 128 + lane * 2;
    float o0 = out[o]     + accx * inv;
    float o1 = out[o + 1] + accy * inv;
    o0 = o0 > 0.f ? o0 : __expf(o0) - 1.f;
    o1 = o1 > 0.f ? o1 : __expf(o1) - 1.f;
    out[o]     = o0;
    out[o + 1] = o1;
}

extern "C" void kernel_launch(void* const* d_in, const int* in_sizes, int n_in,
                              void* d_out, int out_size, void* d_ws, size_t ws_size,
                              hipStream_t stream)
{
    const float* x        = (const float*)d_in[0];
    const int*   ei       = (const int*)d_in[1];
    const float* lin_w    = (const float*)d_in[2];
    const float* att_src  = (const float*)d_in[3];
    const float* att_dst  = (const float*)d_in[4];
    const float* gat_bias = (const float*)d_in[5];
    const float* skip_w   = (const float*)d_in[6];
    const float* skip_b   = (const float*)d_in[7];
    float* out = (float*)d_out;

    const int N = in_sizes[0] / 128;
    const int E = in_sizes[1] / 2;
    const int nb  = (N + 511) >> 9;            // buckets of 512 nodes (<=256)
    const int nba = (E + 4095) / 4096;         // edge blocks

    float* ws   = (float*)d_ws;
    float* asrc = ws;                                   // N*8 f
    float* adst = asrc + (size_t)N * 8;                 // N*8 f
    unsigned short* wt = (unsigned short*)(adst + (size_t)N * 8);     // 32768 bf16
    unsigned short* xh_bf = wt + 32768;                 // N*128 bf16
    int* cntn   = (int*)(xh_bf + (size_t)N * 128);      // N
    int* rowptr = cntn + N;                             // N
    int* esrc   = rowptr + N;                           // E+8 (padded)
    int* bcnt   = esrc + E + 8;                         // 256
    int* fill   = bcnt + 256;                           // 256
    unsigned long long* binned =
        (unsigned long long*)(((size_t)(fill + 256) + 15) & ~(size_t)15);

    // zero: esrc pad (8) + bcnt (256) + fill (256), contiguous
    hipMemsetAsync(esrc + E, 0, (8 + 512) * sizeof(int), stream);

    k0_wt<<<128, 256, 0, stream>>>(lin_w, skip_w, wt);

    (void)hipFuncSetAttribute((const void*)k1_gemm,
                              hipFuncAttributeMaxDynamicSharedMemorySize, 65536);
    int rbs = (N + 127) / 128;
    k1_gemm<<<rbs * 2, 256, 65536, stream>>>(
        x, wt, att_src, att_dst, gat_bias, skip_b, xh_bf, asrc, adst, out, N);

    kA_hist<<<nba, 256, 0, stream>>>(ei, bcnt, E, nb);

    f2<<<nba, 256, 0, stream>>>(ei, bcnt, fill, binned, E, nb);

    f3<<<nb, 256, 0, stream>>>(binned, bcnt, rowptr, cntn, esrc, N, nb);

    k3_agg<<<(N + 3) / 4, 256, 0, stream>>>(rowptr, cntn, esrc, asrc, adst,
                                            (const unsigned int*)xh_bf, out, N);
}